// Round 2
// baseline (15337.842 us; speedup 1.0000x reference)
//
#include <hip/hip_runtime.h>
#include <math.h>

#define TT 96
#define VV 32000
#define EPSF 1e-8f

typedef __attribute__((ext_vector_type(8))) short short8;
typedef __attribute__((ext_vector_type(4))) float f4v;

__device__ __forceinline__ float wsum64(float v){
  #pragma unroll
  for (int m=32;m>0;m>>=1) v += __shfl_xor(v,m);
  return v;
}
__device__ __forceinline__ float sigm(float x){ return 1.0f/(1.0f+expf(-x)); }
__device__ __forceinline__ float softplus(float x){ return x>20.0f ? x : log1pf(expf(x)); }
__device__ __forceinline__ float bf2f(unsigned short u){ return __uint_as_float(((unsigned)u)<<16); }
__device__ __forceinline__ unsigned short f2bf(float f){
  unsigned u = __float_as_uint(f);
  return (unsigned short)((u + 0x7fffu + ((u>>16)&1u)) >> 16);
}

// Manual grid barrier: monotone arrival counter, device scope. All wgs of the
// 256-wg persistent kernel are co-resident (64K threads << 512K capacity).
__device__ __forceinline__ void gbar(unsigned* cnt, unsigned target){
  __syncthreads();
  if (threadIdx.x == 0){
    __threadfence();
    __hip_atomic_fetch_add(cnt, 1u, __ATOMIC_ACQ_REL, __HIP_MEMORY_SCOPE_AGENT);
    while (__hip_atomic_load(cnt, __ATOMIC_ACQUIRE, __HIP_MEMORY_SCOPE_AGENT) < target){
      __builtin_amdgcn_s_sleep(1);
    }
    __threadfence();
  }
  __syncthreads();
}

// Core: 4 rows/wave, 16 cols (4 col-groups of 4), K-chunk of 512 split over 16 lanes.
__device__ __forceinline__ void core_chunk(
  const float4* __restrict__ w0, const float4* __restrict__ w1,
  const float4* __restrict__ w2, const float4* __restrict__ w3,
  const float4* __restrict__ xl, int l, int g, float (&acc)[4][4])
{
  #pragma unroll
  for (int kt=0; kt<8; kt++){
    int i = kt*16 + l;
    float4 a0=w0[i], a1=w1[i], a2=w2[i], a3=w3[i];
    #pragma unroll
    for (int j=0;j<4;j++){
      float4 x = xl[(4*g+j)*129 + i];
      acc[0][j] += a0.x*x.x + a0.y*x.y + a0.z*x.z + a0.w*x.w;
      acc[1][j] += a1.x*x.x + a1.y*x.y + a1.z*x.z + a1.w*x.w;
      acc[2][j] += a2.x*x.x + a2.y*x.y + a2.z*x.z + a2.w*x.w;
      acc[3][j] += a3.x*x.x + a3.y*x.y + a3.z*x.z + a3.w*x.w;
    }
  }
}

__device__ __forceinline__ float reduce_pick(float (&acc)[4][4], int l){
  float r = 0.f;
  #pragma unroll
  for (int ri=0;ri<4;ri++)
  #pragma unroll
  for (int j=0;j<4;j++){
    float v = acc[ri][j];
    v += __shfl_xor(v,1); v += __shfl_xor(v,2);
    v += __shfl_xor(v,4); v += __shfl_xor(v,8);
    if (l == ri*4+j) r = v;
  }
  return r;
}

// ---------------- phase 1: persistent recurrence (manual grid barrier) ----------------
// 256 wgs x 256 thr. Per step, 3 grid syncs:
//   A (all 256 wgs): gates = Whh@h + Pw(+Pa); LSTM pointwise -> h(t+1)
//   B (wgs 0..63):   tf = relu(Wf1_h @ h(t+1) + cf)
//   C (wgs 0..15):   score[f] = G[b,f,:]·tf[b] + gb0[b,f]; softmax/mask/argmax/loss
// (fk eliminated: G = fe^T Wf2 precomputed once in phase 0.)
__global__ __launch_bounds__(256) void k_phase1(
  const float* __restrict__ Whh, float* __restrict__ hall,
  const float* __restrict__ Pw, const float* __restrict__ Pa,
  int* __restrict__ aall, float* __restrict__ c,
  const float* __restrict__ Wf1, const float* __restrict__ cf,
  float* __restrict__ tf,
  const float* __restrict__ Gb, const float* __restrict__ gb0,
  const int* __restrict__ ta, const int* __restrict__ nfp,
  float* __restrict__ loss, unsigned* __restrict__ bar)
{
  __shared__ float4 xl[16*129];
  __shared__ float sg[256];
  __shared__ float sS[64];
  int tid = threadIdx.x, lane = tid & 63, wave = tid >> 6;
  int l = lane & 15, g = lane >> 4;
  int wg = blockIdx.x;
  unsigned rnd = 0;

  for (int t=0; t<TT; t++){
    // ---- phase A: gates + LSTM pointwise (all wgs) ----
    {
      int j0 = wg*4;
      const float4* h4 = (const float4*)hall + (size_t)t*4096;
      float acc[4][4] = {};
      for (int kc=0; kc<2; kc++){
        for (int idx=tid; idx<2048; idx+=256){
          int b = idx>>7, i = idx&127;
          xl[b*129+i] = h4[b*256 + kc*128 + i];
        }
        __syncthreads();
        const float4* w0 = (const float4*)(Whh + (size_t)(wave*1024 + j0+0)*1024) + kc*128;
        const float4* w1 = (const float4*)(Whh + (size_t)(wave*1024 + j0+1)*1024) + kc*128;
        const float4* w2 = (const float4*)(Whh + (size_t)(wave*1024 + j0+2)*1024) + kc*128;
        const float4* w3 = (const float4*)(Whh + (size_t)(wave*1024 + j0+3)*1024) + kc*128;
        core_chunk(w0,w1,w2,w3, xl, l, g, acc);
        __syncthreads();
      }
      float v = reduce_pick(acc, l);
      int r = l>>2;
      int b = g*4 + (l&3);
      int row = wave*1024 + j0 + r;
      float e = Pw[((size_t)(b*96+t))*4096 + row];
      if (t > 0){
        int ai = aall[(t-1)*16 + b];
        e += Pa[((size_t)(b*64+ai))*4096 + row];
      }
      sg[wave*64 + r*16 + b] = v + e;
      __syncthreads();
      if (tid < 64){
        int jj = j0 + (tid>>4), bb = tid&15;
        float ig = sg[  0 + (tid>>4)*16 + bb];
        float fg = sg[ 64 + (tid>>4)*16 + bb];
        float gg = sg[128 + (tid>>4)*16 + bb];
        float og = sg[192 + (tid>>4)*16 + bb];
        int ci = bb*1024 + jj;
        float cn = sigm(fg)*c[ci] + sigm(ig)*tanhf(gg);
        c[ci] = cn;
        hall[((size_t)(t+1)*16 + bb)*1024 + jj] = sigm(og)*tanhf(cn);
      }
    }
    rnd++; gbar(bar, rnd*256u);

    // ---- phase B: tf (wgs 0..63) ----
    if (wg < 64){
      int rl0 = wg*16 + wave*4;
      const float4* h4 = (const float4*)hall + (size_t)(t+1)*4096;
      float acc[4][4] = {};
      for (int kc=0; kc<2; kc++){
        for (int idx=tid; idx<2048; idx+=256){
          int b = idx>>7, i = idx&127;
          xl[b*129+i] = h4[b*256 + kc*128 + i];
        }
        __syncthreads();
        const float4* w0 = (const float4*)(Wf1 + (size_t)(rl0+0)*1536) + kc*128;
        const float4* w1 = (const float4*)(Wf1 + (size_t)(rl0+1)*1536) + kc*128;
        const float4* w2 = (const float4*)(Wf1 + (size_t)(rl0+2)*1536) + kc*128;
        const float4* w3 = (const float4*)(Wf1 + (size_t)(rl0+3)*1536) + kc*128;
        core_chunk(w0,w1,w2,w3, xl, l, g, acc);
        __syncthreads();
      }
      float v = reduce_pick(acc, l);
      int rl = rl0 + (l>>2);
      int b = g*4 + (l&3);
      tf[b*1024 + rl] = fmaxf(v + cf[b*1024 + rl], 0.f);
    }
    rnd++; gbar(bar, rnd*256u);

    // ---- phase C: scores + softmax + argmax + loss (wgs 0..15, wg = b) ----
    if (wg < 16){
      int b = wg;
      float* stf = (float*)xl;
      ((float4*)stf)[tid] = ((const float4*)(tf + b*1024))[tid];
      __syncthreads();
      int f = tid>>2, q = tid&3;
      const float4* G4 = (const float4*)(Gb + (size_t)(b*64+f)*1024);
      const float4* st4 = (const float4*)stf;
      float acc = 0.f;
      for (int j=0;j<64;j++){
        int i = q*64 + j;
        float4 a = G4[i], x = st4[i];
        acc += a.x*x.x + a.y*x.y + a.z*x.z + a.w*x.w;
      }
      acc += __shfl_xor(acc,1);
      acc += __shfl_xor(acc,2);
      if (q==0) sS[f] = acc + gb0[b*64+f];
      __syncthreads();
      if (tid < 64){
        int nf = nfp[b];
        float s = sS[tid];
        float mx = s;
        #pragma unroll
        for (int m=32;m>0;m>>=1) mx = fmaxf(mx, __shfl_xor(mx,m));
        float p = expf(s - mx);
        float ps = wsum64(p);
        p /= ps;
        bool mask = (tid < nf) || (tid == 63);
        float mval = mask ? (p + EPSF) : EPSF;
        float msum = wsum64(mval);
        float bv = mval; int bi2 = tid;
        #pragma unroll
        for (int m=32;m>0;m>>=1){
          float ov = __shfl_xor(bv,m); int oi = __shfl_xor(bi2,m);
          if (ov > bv || (ov == bv && oi < bi2)){ bv = ov; bi2 = oi; }
        }
        int at = ta[b*TT + t];
        float mat = __shfl(mval, at);
        if (tid == 0){
          atomicAdd(loss, -(logf(mat) - logf(msum)));
          aall[t*16 + b] = bi2;
        }
      }
      __syncthreads();
    }
    rnd++; gbar(bar, rnd*256u);
  }
}

// ---------------- phase 2: batched over all (b,t) ----------------

// tcvp[n] = relu(W{c,v,p}1_h @ h_t + Ph[b,aidx] + bias), n = t*16+b
__global__ __launch_bounds__(256) void k2_cvp(
  const float* __restrict__ Wc1, const float* __restrict__ Wv1,
  const float* __restrict__ Wp1, const float* __restrict__ hall,
  const float* __restrict__ Ph, const int* __restrict__ aall,
  const float* __restrict__ bc1, const float* __restrict__ bv1,
  const float* __restrict__ bp1, float* __restrict__ tcvp)
{
  __shared__ float4 xl[16*129];
  int tid = threadIdx.x, lane = tid & 63, wave = tid >> 6;
  int l = lane & 15, g = lane >> 4;
  int seg = blockIdx.x >> 6;
  int rl0 = (blockIdx.x & 63)*16 + wave*4;
  const float* W = (seg==0)?Wc1:(seg==1)?Wv1:Wp1;
  const float4* h4 = (const float4*)hall + (size_t)(16 + blockIdx.y*16)*256;
  float acc[4][4] = {};
  for (int kc=0; kc<2; kc++){
    for (int idx=tid; idx<2048; idx+=256){
      int cc = idx>>7, i = idx&127;
      xl[cc*129+i] = h4[cc*256 + kc*128 + i];
    }
    __syncthreads();
    const float4* w0 = (const float4*)(W + (size_t)(rl0+0)*1536) + kc*128;
    const float4* w1 = (const float4*)(W + (size_t)(rl0+1)*1536) + kc*128;
    const float4* w2 = (const float4*)(W + (size_t)(rl0+2)*1536) + kc*128;
    const float4* w3 = (const float4*)(W + (size_t)(rl0+3)*1536) + kc*128;
    core_chunk(w0,w1,w2,w3, xl, l, g, acc);
    __syncthreads();
  }
  float v = reduce_pick(acc, l);
  int rl = rl0 + (l>>2);
  int n = blockIdx.y*16 + g*4 + (l&3);
  int b = n & 15;
  int ai = aall[n];
  const float* bias = (seg==0)?bc1:(seg==1)?bv1:bp1;
  float vv = v + Ph[((size_t)(b*64+ai))*3072 + seg*1024 + rl] + bias[rl];
  tcvp[(size_t)n*3072 + seg*1024 + rl] = fmaxf(vv, 0.f);
}

// kvoca(bf16) / kpos / zlog for all n
__global__ __launch_bounds__(256) void k2_heads2(
  const float* __restrict__ Wv2, const float* __restrict__ bv2,
  const float* __restrict__ Wp2, const float* __restrict__ bp2,
  const float* __restrict__ Wc2, const float* __restrict__ bc2,
  const float* __restrict__ tcvp, unsigned short* __restrict__ kvh,
  float* __restrict__ kpall, float* __restrict__ zlall)
{
  __shared__ float4 xl[16*129];
  int tid = threadIdx.x, lane = tid & 63, wave = tid >> 6;
  int l = lane & 15, g = lane >> 4;
  int bx = blockIdx.x;
  int seg = (bx < 32) ? 0 : (bx < 39) ? 1 : 2;
  int rb  = (seg==0) ? bx*16 : (seg==1) ? (bx-32)*16 : 0;
  int rl0 = rb + wave*4;
  const float* WS = (seg==0)?Wv2:(seg==1)?Wp2:Wc2;
  int maxr = (seg==0)?511:(seg==1)?99:0;
  int xoff4 = (seg==0)?256:(seg==1)?512:0;
  const float4* X4 = (const float4*)tcvp;
  float acc[4][4] = {};
  for (int kc=0; kc<2; kc++){
    for (int idx=tid; idx<2048; idx+=256){
      int cc = idx>>7, i = idx&127;
      xl[cc*129+i] = X4[(size_t)(blockIdx.y*16+cc)*768 + xoff4 + kc*128 + i];
    }
    __syncthreads();
    const float4* w0 = (const float4*)(WS + (size_t)min(rl0+0,maxr)*1024) + kc*128;
    const float4* w1 = (const float4*)(WS + (size_t)min(rl0+1,maxr)*1024) + kc*128;
    const float4* w2 = (const float4*)(WS + (size_t)min(rl0+2,maxr)*1024) + kc*128;
    const float4* w3 = (const float4*)(WS + (size_t)min(rl0+3,maxr)*1024) + kc*128;
    core_chunk(w0,w1,w2,w3, xl, l, g, acc);
    __syncthreads();
  }
  float v = reduce_pick(acc, l);
  int rl = rl0 + (l>>2);
  int n = blockIdx.y*16 + g*4 + (l&3);
  if (seg==0) kvh[(size_t)n*512 + rl] = f2bf(v + bv2[rl]);
  else if (seg==1){ if (rl < 100) kpall[n*128 + rl] = v + bp2[rl]; }
  else { if (rl == 0) zlall[n] = v + bc2[0]; }
}

// vocab GEMM (bf16 MFMA, 64x64 per wave) with fused per-64-row logsumexp partials
__global__ __launch_bounds__(256) void k2_vocab(
  const unsigned short* __restrict__ embh, const unsigned short* __restrict__ kvh,
  float2* __restrict__ part)
{
  int wid = blockIdx.x*4 + (threadIdx.x>>6);
  int lane = threadIdx.x & 63;
  int mtile = wid % 500, ntile = wid / 500;
  int mrow = mtile*64 + (lane&15);
  int ncol = ntile*64 + (lane&15);
  int ko = (lane>>4)*8;
  f4v acc[4][4];
  #pragma unroll
  for (int i=0;i<4;i++)
  #pragma unroll
  for (int j=0;j<4;j++)
  #pragma unroll
  for (int r=0;r<4;r++) acc[i][j][r] = 0.f;
  for (int kk=0; kk<512; kk+=32){
    short8 af[4], bfr[4];
    #pragma unroll
    for (int i=0;i<4;i++)
      af[i] = *(const short8*)(embh + (size_t)(mrow+16*i)*512 + kk + ko);
    #pragma unroll
    for (int i=0;i<4;i++)
      bfr[i] = *(const short8*)(kvh + (size_t)(ncol+16*i)*512 + kk + ko);
    #pragma unroll
    for (int i=0;i<4;i++)
      #pragma unroll
      for (int j=0;j<4;j++)
        acc[i][j] = __builtin_amdgcn_mfma_f32_16x16x32_bf16(af[i], bfr[j], acc[i][j], 0,0,0);
  }
  int q = lane>>4;
  #pragma unroll
  for (int j=0;j<4;j++){
    float mx = -3.4e38f;
    #pragma unroll
    for (int i=0;i<4;i++)
    #pragma unroll
    for (int r=0;r<4;r++) mx = fmaxf(mx, acc[i][j][r]);
    mx = fmaxf(mx, __shfl_xor(mx,16));
    mx = fmaxf(mx, __shfl_xor(mx,32));
    float s = 0.f;
    #pragma unroll
    for (int i=0;i<4;i++)
    #pragma unroll
    for (int r=0;r<4;r++) s += expf(acc[i][j][r] - mx);
    s += __shfl_xor(s,16);
    s += __shfl_xor(s,32);
    if (q==0){
      int col = ntile*64 + 16*j + (lane&15);
      part[(size_t)col*500 + mtile] = make_float2(mx, s);
    }
  }
}

// per-n: merge partials -> logZ; direct dot for logit[w]; vocab loss (z==0)
__global__ __launch_bounds__(256) void k2_vfin(
  const float2* __restrict__ part, const unsigned short* __restrict__ embh,
  const unsigned short* __restrict__ kvh, const int* __restrict__ tw,
  const int* __restrict__ tz, float* __restrict__ loss)
{
  __shared__ float red[4];
  int n = blockIdx.x, tid = threadIdx.x;
  int t = n>>4, b = n&15;
  float mx = -3.4e38f;
  for (int i=tid; i<500; i+=256) mx = fmaxf(mx, part[(size_t)n*500+i].x);
  #pragma unroll
  for (int m=32;m>0;m>>=1) mx = fmaxf(mx, __shfl_xor(mx,m));
  if ((tid&63)==0) red[tid>>6] = mx;
  __syncthreads();
  float M = fmaxf(fmaxf(red[0],red[1]), fmaxf(red[2],red[3]));
  __syncthreads();
  float s = 0.f;
  for (int i=tid; i<500; i+=256){
    float2 p = part[(size_t)n*500+i];
    s += p.y * expf(p.x - M);
  }
  s = wsum64(s);
  if ((tid&63)==0) red[tid>>6] = s;
  __syncthreads();
  float S = red[0]+red[1]+red[2]+red[3];
  __syncthreads();
  int w = tw[b*96+t];
  float d = 0.f;
  {
    const unsigned short* er = embh + (size_t)w*512;
    const unsigned short* kr = kvh + (size_t)n*512;
    for (int i=tid; i<512; i+=256) d += bf2f(er[i])*bf2f(kr[i]);
  }
  d = wsum64(d);
  if ((tid&63)==0) red[tid>>6] = d;
  __syncthreads();
  if (tid==0 && tz[b*96+t]==0){
    float D = red[0]+red[1]+red[2]+red[3];
    atomicAdd(loss, -(D - (M + logf(S))));
  }
}

// per-n: z loss + position loss
__global__ __launch_bounds__(128) void k2_posz(
  const float* __restrict__ kpall, const float* __restrict__ zlall,
  const float* __restrict__ WP, const float* __restrict__ bP,
  const float* __restrict__ pmask, const int* __restrict__ tw,
  const int* __restrict__ ta, const int* __restrict__ tz,
  float* __restrict__ loss)
{
  __shared__ float pp[100];
  int n = blockIdx.x, tid = threadIdx.x;
  int t = n>>4, b = n&15;
  if (tid < 100){
    float s = bP[tid];
    const float* wr = WP + tid*100;
    const float* kp = kpall + n*128;
    for (int j=0;j<100;j++) s += wr[j]*kp[j];
    pp[tid] = s;
  }
  __syncthreads();
  if (tid == 0){
    float u = zlall[n];
    int z = tz[b*96+t], w = tw[b*96+t], at = ta[b*96+t];
    float tot = z ? softplus(-u) : softplus(u);
    if (z){
      float mxv = -1e30f;
      for (int l2=0;l2<100;l2++) mxv = fmaxf(mxv, pp[l2]);
      float se = 0.f;
      for (int l2=0;l2<100;l2++) se += expf(pp[l2]-mxv);
      const float* pm = pmask + ((size_t)b*64 + at)*100;
      float msum = 0.f, mw = 0.f;
      for (int l2=0;l2<100;l2++){
        float m = pm[l2]*(expf(pp[l2]-mxv)/se) + EPSF;
        msum += m;
        if (l2==w) mw = m;
      }
      tot += -(logf(mw) - logf(msum));
    }
    atomicAdd(loss, tot);
  }
}

// ---------------- phase 0: once-per-launch precompute ----------------

__global__ void k_cvt_emb(const float* __restrict__ emb, unsigned* __restrict__ out){
  const int n = VV*512/2;
  for (int idx = blockIdx.x*256 + threadIdx.x; idx < n; idx += gridDim.x*256){
    float2 v = ((const float2*)emb)[idx];
    unsigned a = __float_as_uint(v.x), b = __float_as_uint(v.y);
    unsigned ra = (a + 0x7fffu + ((a>>16)&1u)) >> 16;
    unsigned rb = (b + 0x7fffu + ((b>>16)&1u)) >> 16;
    out[idx] = ra | (rb<<16);
  }
}

__global__ void k_setup(const float* __restrict__ fe, const int* __restrict__ nfp,
                        float* __restrict__ e_k){
  int b = blockIdx.x, tid = threadIdx.x;
  int nf = nfp[b];
  for (int d=tid; d<512; d+=256){
    float s = 0.f;
    for (int f=0; f<nf; f++) s += fe[((size_t)b*64+f)*512 + d];
    e_k[b*512+d] = s/(float)nf;
  }
}

__global__ __launch_bounds__(256) void k_pre_pa(
  const float* __restrict__ Wih, const float* __restrict__ fe, float* __restrict__ Pa)
{
  __shared__ float4 xl[16*129];
  int tid = threadIdx.x, lane = tid & 63, wave = tid >> 6;
  int l = lane & 15, g = lane >> 4;
  int row0 = blockIdx.x*16 + wave*4;
  int c0 = blockIdx.y*16;
  const float4* fe4 = (const float4*)fe;
  for (int idx=tid; idx<2048; idx+=256){
    int cc = idx>>7, i = idx&127;
    xl[cc*129+i] = fe4[(size_t)(c0+cc)*128 + i];
  }
  __syncthreads();
  const float4* w0 = (const float4*)(Wih + (size_t)(row0+0)*1124);
  const float4* w1 = (const float4*)(Wih + (size_t)(row0+1)*1124);
  const float4* w2 = (const float4*)(Wih + (size_t)(row0+2)*1124);
  const float4* w3 = (const float4*)(Wih + (size_t)(row0+3)*1124);
  float acc[4][4] = {};
  core_chunk(w0,w1,w2,w3, xl, l, g, acc);
  float v = reduce_pick(acc, l);
  int row = row0 + (l>>2), c = c0 + g*4 + (l&3);
  Pa[(size_t)c*4096 + row] = v;
}

__global__ __launch_bounds__(256) void k_pre_ph(
  const float* __restrict__ Wc1, const float* __restrict__ Wv1,
  const float* __restrict__ Wp1, const float* __restrict__ fe, float* __restrict__ Ph)
{
  __shared__ float4 xl[16*129];
  int tid = threadIdx.x, lane = tid & 63, wave = tid >> 6;
  int l = lane & 15, g = lane >> 4;
  int row0 = blockIdx.x*16 + wave*4;
  int head = row0 >> 10, rl0 = row0 & 1023;
  const float* W = (head==0)?Wc1:(head==1)?Wv1:Wp1;
  int c0 = blockIdx.y*16;
  const float4* fe4 = (const float4*)fe;
  for (int idx=tid; idx<2048; idx+=256){
    int cc = idx>>7, i = idx&127;
    xl[cc*129+i] = fe4[(size_t)(c0+cc)*128 + i];
  }
  __syncthreads();
  const float4* w0 = (const float4*)(W + (size_t)(rl0+0)*1536 + 1024);
  const float4* w1 = (const float4*)(W + (size_t)(rl0+1)*1536 + 1024);
  const float4* w2 = (const float4*)(W + (size_t)(rl0+2)*1536 + 1024);
  const float4* w3 = (const float4*)(W + (size_t)(rl0+3)*1536 + 1024);
  float acc[4][4] = {};
  core_chunk(w0,w1,w2,w3, xl, l, g, acc);
  float v = reduce_pick(acc, l);
  int row = row0 + (l>>2), c = c0 + g*4 + (l&3);
  Ph[(size_t)c*3072 + row] = v;
}

__global__ __launch_bounds__(256) void k_pre_pw(
  const float* __restrict__ Wih, const float* __restrict__ emb,
  const int* __restrict__ tw, const int* __restrict__ tz,
  const float* __restrict__ bih, const float* __restrict__ bhh,
  float* __restrict__ Pw)
{
  __shared__ float4 xl[16*129];
  int tid = threadIdx.x, lane = tid & 63, wave = tid >> 6;
  int l = lane & 15, g = lane >> 4;
  int row0 = blockIdx.x*16 + wave*4;
  int c0 = blockIdx.y*16;
  for (int idx=tid; idx<2048; idx+=256){
    int cc = idx>>7, i = idx&127;
    int c = c0+cc, b = c/96, t2 = c - b*96;
    int w=0, z=0;
    if (t2>0){ w = tw[b*96+t2-1]; z = tz[b*96+t2-1]; }
    float4 v = make_float4(0.f,0.f,0.f,0.f);
    if (z==0) v = ((const float4*)emb)[(size_t)w*128 + i];
    xl[cc*129+i] = v;
  }
  __syncthreads();
  const float4* w0 = (const float4*)(Wih + (size_t)(row0+0)*1124 + 512);
  const float4* w1 = (const float4*)(Wih + (size_t)(row0+1)*1124 + 512);
  const float4* w2 = (const float4*)(Wih + (size_t)(row0+2)*1124 + 512);
  const float4* w3 = (const float4*)(Wih + (size_t)(row0+3)*1124 + 512);
  float acc[4][4] = {};
  core_chunk(w0,w1,w2,w3, xl, l, g, acc);
  float v = reduce_pick(acc, l);
  int row = row0 + (l>>2), c = c0 + g*4 + (l&3);
  int b = c/96, t2 = c - b*96;
  int w=0, z=0;
  if (t2>0){ w = tw[b*96+t2-1]; z = tz[b*96+t2-1]; }
  v += bih[row] + bhh[row];
  if (z) v += Wih[(size_t)row*1124 + 1024 + w];
  Pw[(size_t)c*4096 + row] = v;
}

__global__ __launch_bounds__(256) void k_pre_cf(
  const float* __restrict__ Wf1, const float* __restrict__ bf1,
  const float* __restrict__ e_k, float* __restrict__ cf)
{
  __shared__ float4 xl[16*129];
  int tid = threadIdx.x, lane = tid & 63, wave = tid >> 6;
  int l = lane & 15, g = lane >> 4;
  int row0 = blockIdx.x*16 + wave*4;
  const float4* ek4 = (const float4*)e_k;
  for (int idx=tid; idx<2048; idx+=256){
    int cc = idx>>7, i = idx&127;
    xl[cc*129+i] = ek4[cc*128 + i];
  }
  __syncthreads();
  const float4* w0 = (const float4*)(Wf1 + (size_t)(row0+0)*1536 + 1024);
  const float4* w1 = (const float4*)(Wf1 + (size_t)(row0+1)*1536 + 1024);
  const float4* w2 = (const float4*)(Wf1 + (size_t)(row0+2)*1536 + 1024);
  const float4* w3 = (const float4*)(Wf1 + (size_t)(row0+3)*1536 + 1024);
  float acc[4][4] = {};
  core_chunk(w0,w1,w2,w3, xl, l, g, acc);
  float v = reduce_pick(acc, l);
  int row = row0 + (l>>2), b = g*4 + (l&3);
  cf[b*1024 + row] = v + bf1[row];
}

// Gb[(b*64+f)][k] = sum_d fe[b,f,d] * Wf2[d][k]   (1024 x 1024, K=512)
__global__ __launch_bounds__(256) void k_pre_g(
  const float* __restrict__ Wf2, const float* __restrict__ fe, float* __restrict__ Gb)
{
  __shared__ float fs[16][128];
  int tid = threadIdx.x;
  int r0 = blockIdx.x*16;
  int k0 = blockIdx.y*256;
  float acc[16] = {};
  for (int dc=0; dc<4; dc++){
    for (int idx=tid; idx<2048; idx+=256){
      int r = idx>>7, d = idx&127;
      fs[r][d] = fe[(size_t)(r0+r)*512 + dc*128 + d];
    }
    __syncthreads();
    for (int d=0; d<128; d++){
      float w = Wf2[(size_t)(dc*128+d)*1024 + k0 + tid];
      #pragma unroll
      for (int r=0;r<16;r++) acc[r] += fs[r][d]*w;
    }
    __syncthreads();
  }
  #pragma unroll
  for (int r=0;r<16;r++) Gb[(size_t)(r0+r)*1024 + k0 + tid] = acc[r];
}

// gb0[b,f] = fe[b,f,:] . bf2
__global__ __launch_bounds__(256) void k_gb0(
  const float* __restrict__ fe, const float* __restrict__ bf2, float* __restrict__ gb0)
{
  int b = blockIdx.x;
  int f = threadIdx.x>>2, q = threadIdx.x&3;
  const float4* fe4 = (const float4*)(fe + ((size_t)b*64+f)*512);
  const float4* b4 = (const float4*)bf2;
  float acc = 0.f;
  for (int j=0;j<32;j++){
    int i = q*32+j;
    float4 a = fe4[i], x = b4[i];
    acc += a.x*x.x + a.y*x.y + a.z*x.z + a.w*x.w;
  }
  acc += __shfl_xor(acc,1);
  acc += __shfl_xor(acc,2);
  if (q==0) gb0[b*64+f] = acc;
}

__global__ void k_out(const float* __restrict__ loss, float* __restrict__ out){
  out[0] = loss[0];
}

extern "C" void kernel_launch(void* const* d_in, const int* in_sizes, int n_in,
                              void* d_out, int out_size, void* d_ws, size_t ws_size,
                              hipStream_t stream)
{
  const float* fe   = (const float*)d_in[0];
  const float* pmask= (const float*)d_in[1];
  const float* emb  = (const float*)d_in[2];
  const float* Wih  = (const float*)d_in[3];
  const float* Whh  = (const float*)d_in[4];
  const float* bih  = (const float*)d_in[5];
  const float* bhh  = (const float*)d_in[6];
  const float* Wf1  = (const float*)d_in[7];
  const float* bf1  = (const float*)d_in[8];
  const float* Wf2  = (const float*)d_in[9];
  const float* bf2  = (const float*)d_in[10];
  const float* Wc1  = (const float*)d_in[11];
  const float* bc1  = (const float*)d_in[12];
  const float* Wc2  = (const float*)d_in[13];
  const float* bc2  = (const float*)d_in[14];
  const float* Wv1  = (const float*)d_in[15];
  const float* bv1  = (const float*)d_in[16];
  const float* Wv2  = (const float*)d_in[17];
  const float* bv2  = (const float*)d_in[18];
  const float* Wp1  = (const float*)d_in[19];
  const float* bp1  = (const float*)d_in[20];
  const float* Wp2  = (const float*)d_in[21];
  const float* bp2  = (const float*)d_in[22];
  const float* WP   = (const float*)d_in[23];
  const float* bP   = (const float*)d_in[24];
  const int* tw  = (const int*)d_in[25];
  const int* ta  = (const int*)d_in[26];
  const int* tz  = (const int*)d_in[27];
  const int* nfp = (const int*)d_in[28];

  float* w = (float*)d_ws;
  float*    loss  = w + 0;                        // 16 (bar counter at w+8)
  unsigned* bar   = (unsigned*)(w + 8);
  float*    c     = w + 16;                       // 16384
  float*    hall  = w + 16400;                    // 97*16384 = 1589248 (slot0 zeroed)
  int*      aall  = (int*)(w + 1605648);          // 1536
  float*    tf    = w + 1607184;                  // 16384
  float*    gb0   = w + 1623568;                  // 1024
  float*    e_k   = w + 1631760;                  // 8192
  float*    cf    = w + 1639952;                  // 16384
  float*    kpall = w + 1656336;                  // 196608
  float*    zlall = w + 1852944;                  // 1536
  float*    tcvp  = w + 1854480;                  // 4718592 (phase 2 only)
  float*    Gb    = w + 1854480;                  // 1048576 — aliases tcvp; dead before k2_cvp runs
  float2*   part  = (float2*)(w + 6573072);       // 1536*500*2 floats
  unsigned short* kvh = (unsigned short*)(w + 8109072);  // 786432 ushorts
  float*    Pa    = w + 8502288;                  // 4194304
  float*    Ph    = w + 12696592;                 // 3145728
  float*    Pw    = w + 15842320;                 // 6291456
  unsigned* embbf = (unsigned*)(w + 22133776);    // 8192000 uints
  const unsigned short* embh = (const unsigned short*)embbf;

  // zero loss+bar, c, hall slot 0
  hipMemsetAsync(d_ws, 0, (size_t)(16 + 16384 + 16384)*4, stream);
  k_cvt_emb<<<8192,256,0,stream>>>(emb, embbf);
  k_setup<<<16,256,0,stream>>>(fe, nfp, e_k);
  k_pre_pa<<<dim3(256,64),256,0,stream>>>(Wih, fe, Pa);
  k_pre_ph<<<dim3(192,64),256,0,stream>>>(Wc1, Wv1, Wp1, fe, Ph);
  k_pre_pw<<<dim3(256,96),256,0,stream>>>(Wih, emb, tw, tz, bih, bhh, Pw);
  k_pre_cf<<<64,256,0,stream>>>(Wf1, bf1, e_k, cf);
  k_pre_g<<<dim3(64,4),256,0,stream>>>(Wf2, fe, Gb);
  k_gb0<<<16,256,0,stream>>>(fe, bf2, gb0);

  // phase 1: one persistent kernel, manual grid barrier (graph-capture safe)
  k_phase1<<<256,256,0,stream>>>(Whh, hall, Pw, Pa, aall, c, Wf1, cf, tf,
                                 Gb, gb0, ta, nfp, loss, bar);

  k2_cvp<<<dim3(192,96),256,0,stream>>>(Wc1, Wv1, Wp1, hall, Ph, aall,
                                        bc1, bv1, bp1, tcvp);
  k2_heads2<<<dim3(40,96),256,0,stream>>>(Wv2, bv2, Wp2, bp2, Wc2, bc2,
                                          tcvp, kvh, kpall, zlall);
  k2_vocab<<<3000,256,0,stream>>>(embh, kvh, part);
  k2_vfin<<<1536,256,0,stream>>>(part, embh, kvh, tw, tz, loss);
  k2_posz<<<1536,128,0,stream>>>(kpall, zlall, WP, bP, pmask, tw, ta, tz, loss);
  k_out<<<1,1,0,stream>>>(loss, (float*)d_out);
}

// Round 3
// 5404.386 us; speedup vs baseline: 2.8380x; 2.8380x over previous
//
#include <hip/hip_runtime.h>
#include <math.h>

#define TT 96
#define VV 32000
#define EPSF 1e-8f

typedef __attribute__((ext_vector_type(8))) short short8;
typedef __attribute__((ext_vector_type(4))) float f4v;

__device__ __forceinline__ float wsum64(float v){
  #pragma unroll
  for (int m=32;m>0;m>>=1) v += __shfl_xor(v,m);
  return v;
}
__device__ __forceinline__ float sigm(float x){ return 1.0f/(1.0f+expf(-x)); }
__device__ __forceinline__ float softplus(float x){ return x>20.0f ? x : log1pf(expf(x)); }
__device__ __forceinline__ float bf2f(unsigned short u){ return __uint_as_float(((unsigned)u)<<16); }
__device__ __forceinline__ unsigned short f2bf(float f){
  unsigned u = __float_as_uint(f);
  return (unsigned short)((u + 0x7fffu + ((u>>16)&1u)) >> 16);
}

// Device-coherent (L1/L2-bypassing) relaxed stores/loads for cross-wg data.
__device__ __forceinline__ void st_dc(float* p, float v){
  __hip_atomic_store(p, v, __ATOMIC_RELAXED, __HIP_MEMORY_SCOPE_AGENT);
}
__device__ __forceinline__ void st_dc_i(int* p, int v){
  __hip_atomic_store(p, v, __ATOMIC_RELAXED, __HIP_MEMORY_SCOPE_AGENT);
}
__device__ __forceinline__ int ld_dc_i(const int* p){
  return __hip_atomic_load(p, __ATOMIC_RELAXED, __HIP_MEMORY_SCOPE_AGENT);
}
__device__ __forceinline__ float2 ld_dc_2(const float* p){
  union { unsigned long long u; float2 f; } cv;
  cv.u = __hip_atomic_load((const unsigned long long*)p, __ATOMIC_RELAXED, __HIP_MEMORY_SCOPE_AGENT);
  return cv.f;
}

// Fence-free grid barrier: relaxed monotone arrival counter at device scope.
// Correctness: all cross-phase data is published with sc0/sc1 stores; the
// __syncthreads() drains each wave's vmcnt, so data is at the coherence point
// before the (relaxed) arrival increment. No L2 writeback/invalidate emitted.
__device__ __forceinline__ void gbar(unsigned* cnt, unsigned target){
  __syncthreads();
  if (threadIdx.x == 0){
    __hip_atomic_fetch_add(cnt, 1u, __ATOMIC_RELAXED, __HIP_MEMORY_SCOPE_AGENT);
    while (__hip_atomic_load(cnt, __ATOMIC_RELAXED, __HIP_MEMORY_SCOPE_AGENT) < target){
      __builtin_amdgcn_s_sleep(8);
    }
    asm volatile("" ::: "memory");
  }
  __syncthreads();
}

// Core: 4 rows/wave, 16 cols (4 col-groups of 4), K-chunk of 512 split over 16 lanes.
__device__ __forceinline__ void core_chunk(
  const float4* __restrict__ w0, const float4* __restrict__ w1,
  const float4* __restrict__ w2, const float4* __restrict__ w3,
  const float4* __restrict__ xl, int l, int g, float (&acc)[4][4])
{
  #pragma unroll
  for (int kt=0; kt<8; kt++){
    int i = kt*16 + l;
    float4 a0=w0[i], a1=w1[i], a2=w2[i], a3=w3[i];
    #pragma unroll
    for (int j=0;j<4;j++){
      float4 x = xl[(4*g+j)*129 + i];
      acc[0][j] += a0.x*x.x + a0.y*x.y + a0.z*x.z + a0.w*x.w;
      acc[1][j] += a1.x*x.x + a1.y*x.y + a1.z*x.z + a1.w*x.w;
      acc[2][j] += a2.x*x.x + a2.y*x.y + a2.z*x.z + a2.w*x.w;
      acc[3][j] += a3.x*x.x + a3.y*x.y + a3.z*x.z + a3.w*x.w;
    }
  }
}

__device__ __forceinline__ float reduce_pick(float (&acc)[4][4], int l){
  float r = 0.f;
  #pragma unroll
  for (int ri=0;ri<4;ri++)
  #pragma unroll
  for (int j=0;j<4;j++){
    float v = acc[ri][j];
    v += __shfl_xor(v,1); v += __shfl_xor(v,2);
    v += __shfl_xor(v,4); v += __shfl_xor(v,8);
    if (l == ri*4+j) r = v;
  }
  return r;
}

// ---------------- phase 1: persistent recurrence (fence-free grid barrier) ----------------
// 256 wgs x 256 thr. Per step, 3 grid syncs:
//   A (all 256 wgs): gates = Whh@h + Pw(+Pa); LSTM pointwise -> h(t+1)  [h published sc1]
//   B (wgs 0..63):   tf = relu(Wf1_h @ h(t+1) + cf)                      [tf published sc1]
//   C (wgs 0..15):   score[f] = G[b,f,:]·tf[b] + gb0[b,f]; softmax/argmax/loss [aall sc1]
// hall/aall are write-once per address (aall padded to 64 ints/step, 256B-aligned)
// so readers may use plain cached loads; tf is reused so readers bypass caches.
__global__ __launch_bounds__(256) void k_phase1(
  const float* __restrict__ Whh, float* __restrict__ hall,
  const float* __restrict__ Pw, const float* __restrict__ Pa,
  int* __restrict__ aall, float* __restrict__ c,
  const float* __restrict__ Wf1, const float* __restrict__ cf,
  float* __restrict__ tf,
  const float* __restrict__ Gb, const float* __restrict__ gb0,
  const int* __restrict__ ta, const int* __restrict__ nfp,
  float* __restrict__ loss, unsigned* __restrict__ bar)
{
  __shared__ float4 xl[16*129];
  __shared__ float sg[256];
  __shared__ float sS[64];
  int tid = threadIdx.x, lane = tid & 63, wave = tid >> 6;
  int l = lane & 15, g = lane >> 4;
  int wg = blockIdx.x;
  unsigned rnd = 0;

  for (int t=0; t<TT; t++){
    // ---- phase A: gates + LSTM pointwise (all wgs) ----
    {
      int j0 = wg*4;
      const float4* h4 = (const float4*)hall + (size_t)t*4096;
      float acc[4][4] = {};
      for (int kc=0; kc<2; kc++){
        for (int idx=tid; idx<2048; idx+=256){
          int b = idx>>7, i = idx&127;
          xl[b*129+i] = h4[b*256 + kc*128 + i];
        }
        __syncthreads();
        const float4* w0 = (const float4*)(Whh + (size_t)(wave*1024 + j0+0)*1024) + kc*128;
        const float4* w1 = (const float4*)(Whh + (size_t)(wave*1024 + j0+1)*1024) + kc*128;
        const float4* w2 = (const float4*)(Whh + (size_t)(wave*1024 + j0+2)*1024) + kc*128;
        const float4* w3 = (const float4*)(Whh + (size_t)(wave*1024 + j0+3)*1024) + kc*128;
        core_chunk(w0,w1,w2,w3, xl, l, g, acc);
        __syncthreads();
      }
      float v = reduce_pick(acc, l);
      int r = l>>2;
      int b = g*4 + (l&3);
      int row = wave*1024 + j0 + r;
      float e = Pw[((size_t)(b*96+t))*4096 + row];
      if (t > 0){
        int ai = ld_dc_i(&aall[(t-1)*64 + b]);
        e += Pa[((size_t)(b*64+ai))*4096 + row];
      }
      sg[wave*64 + r*16 + b] = v + e;
      __syncthreads();
      if (tid < 64){
        int jj = j0 + (tid>>4), bb = tid&15;
        float ig = sg[  0 + (tid>>4)*16 + bb];
        float fg = sg[ 64 + (tid>>4)*16 + bb];
        float gg = sg[128 + (tid>>4)*16 + bb];
        float og = sg[192 + (tid>>4)*16 + bb];
        int ci = bb*1024 + jj;
        float cn = sigm(fg)*c[ci] + sigm(ig)*tanhf(gg);
        c[ci] = cn;   // owner-exclusive: plain cached access is safe
        st_dc(&hall[((size_t)(t+1)*16 + bb)*1024 + jj], sigm(og)*tanhf(cn));
      }
    }
    rnd++; gbar(bar, rnd*256u);

    // ---- phase B: tf (wgs 0..63) ----
    if (wg < 64){
      int rl0 = wg*16 + wave*4;
      const float4* h4 = (const float4*)hall + (size_t)(t+1)*4096;
      float acc[4][4] = {};
      for (int kc=0; kc<2; kc++){
        for (int idx=tid; idx<2048; idx+=256){
          int b = idx>>7, i = idx&127;
          xl[b*129+i] = h4[b*256 + kc*128 + i];
        }
        __syncthreads();
        const float4* w0 = (const float4*)(Wf1 + (size_t)(rl0+0)*1536) + kc*128;
        const float4* w1 = (const float4*)(Wf1 + (size_t)(rl0+1)*1536) + kc*128;
        const float4* w2 = (const float4*)(Wf1 + (size_t)(rl0+2)*1536) + kc*128;
        const float4* w3 = (const float4*)(Wf1 + (size_t)(rl0+3)*1536) + kc*128;
        core_chunk(w0,w1,w2,w3, xl, l, g, acc);
        __syncthreads();
      }
      float v = reduce_pick(acc, l);
      int rl = rl0 + (l>>2);
      int b = g*4 + (l&3);
      st_dc(&tf[b*1024 + rl], fmaxf(v + cf[b*1024 + rl], 0.f));
    }
    rnd++; gbar(bar, rnd*256u);

    // ---- phase C: scores + softmax + argmax + loss (wgs 0..15, wg = b) ----
    if (wg < 16){
      int b = wg;
      float* stf = (float*)xl;
      {
        const float* src = tf + b*1024;
        float2 c0 = ld_dc_2(src + 4*tid + 0);
        float2 c1 = ld_dc_2(src + 4*tid + 2);
        ((float2*)stf)[2*tid+0] = c0;
        ((float2*)stf)[2*tid+1] = c1;
      }
      __syncthreads();
      int f = tid>>2, q = tid&3;
      const float4* G4 = (const float4*)(Gb + (size_t)(b*64+f)*1024);
      const float4* st4 = (const float4*)stf;
      float acc = 0.f;
      for (int j=0;j<64;j++){
        int i = q*64 + j;
        float4 a = G4[i], x = st4[i];
        acc += a.x*x.x + a.y*x.y + a.z*x.z + a.w*x.w;
      }
      acc += __shfl_xor(acc,1);
      acc += __shfl_xor(acc,2);
      if (q==0) sS[f] = acc + gb0[b*64+f];
      __syncthreads();
      if (tid < 64){
        int nf = nfp[b];
        float s = sS[tid];
        float mx = s;
        #pragma unroll
        for (int m=32;m>0;m>>=1) mx = fmaxf(mx, __shfl_xor(mx,m));
        float p = expf(s - mx);
        float ps = wsum64(p);
        p /= ps;
        bool mask = (tid < nf) || (tid == 63);
        float mval = mask ? (p + EPSF) : EPSF;
        float msum = wsum64(mval);
        float bv = mval; int bi2 = tid;
        #pragma unroll
        for (int m=32;m>0;m>>=1){
          float ov = __shfl_xor(bv,m); int oi = __shfl_xor(bi2,m);
          if (ov > bv || (ov == bv && oi < bi2)){ bv = ov; bi2 = oi; }
        }
        int at = ta[b*TT + t];
        float mat = __shfl(mval, at);
        if (tid == 0){
          atomicAdd(loss, -(logf(mat) - logf(msum)));
          st_dc_i(&aall[t*64 + b], bi2);
        }
      }
      __syncthreads();
    }
    rnd++; gbar(bar, rnd*256u);
  }
}

// ---------------- phase 2: batched over all (b,t) ----------------

// tcvp[n] = relu(W{c,v,p}1_h @ h_t + Ph[b,aidx] + bias), n = t*16+b
__global__ __launch_bounds__(256) void k2_cvp(
  const float* __restrict__ Wc1, const float* __restrict__ Wv1,
  const float* __restrict__ Wp1, const float* __restrict__ hall,
  const float* __restrict__ Ph, const int* __restrict__ aall,
  const float* __restrict__ bc1, const float* __restrict__ bv1,
  const float* __restrict__ bp1, float* __restrict__ tcvp)
{
  __shared__ float4 xl[16*129];
  int tid = threadIdx.x, lane = tid & 63, wave = tid >> 6;
  int l = lane & 15, g = lane >> 4;
  int seg = blockIdx.x >> 6;
  int rl0 = (blockIdx.x & 63)*16 + wave*4;
  const float* W = (seg==0)?Wc1:(seg==1)?Wv1:Wp1;
  const float4* h4 = (const float4*)hall + (size_t)(16 + blockIdx.y*16)*256;
  float acc[4][4] = {};
  for (int kc=0; kc<2; kc++){
    for (int idx=tid; idx<2048; idx+=256){
      int cc = idx>>7, i = idx&127;
      xl[cc*129+i] = h4[cc*256 + kc*128 + i];
    }
    __syncthreads();
    const float4* w0 = (const float4*)(W + (size_t)(rl0+0)*1536) + kc*128;
    const float4* w1 = (const float4*)(W + (size_t)(rl0+1)*1536) + kc*128;
    const float4* w2 = (const float4*)(W + (size_t)(rl0+2)*1536) + kc*128;
    const float4* w3 = (const float4*)(W + (size_t)(rl0+3)*1536) + kc*128;
    core_chunk(w0,w1,w2,w3, xl, l, g, acc);
    __syncthreads();
  }
  float v = reduce_pick(acc, l);
  int rl = rl0 + (l>>2);
  int n = blockIdx.y*16 + g*4 + (l&3);
  int b = n & 15;
  int ai = aall[(n>>4)*64 + (n&15)];
  const float* bias = (seg==0)?bc1:(seg==1)?bv1:bp1;
  float vv = v + Ph[((size_t)(b*64+ai))*3072 + seg*1024 + rl] + bias[rl];
  tcvp[(size_t)n*3072 + seg*1024 + rl] = fmaxf(vv, 0.f);
}

// kvoca(bf16) / kpos / zlog for all n
__global__ __launch_bounds__(256) void k2_heads2(
  const float* __restrict__ Wv2, const float* __restrict__ bv2,
  const float* __restrict__ Wp2, const float* __restrict__ bp2,
  const float* __restrict__ Wc2, const float* __restrict__ bc2,
  const float* __restrict__ tcvp, unsigned short* __restrict__ kvh,
  float* __restrict__ kpall, float* __restrict__ zlall)
{
  __shared__ float4 xl[16*129];
  int tid = threadIdx.x, lane = tid & 63, wave = tid >> 6;
  int l = lane & 15, g = lane >> 4;
  int bx = blockIdx.x;
  int seg = (bx < 32) ? 0 : (bx < 39) ? 1 : 2;
  int rb  = (seg==0) ? bx*16 : (seg==1) ? (bx-32)*16 : 0;
  int rl0 = rb + wave*4;
  const float* WS = (seg==0)?Wv2:(seg==1)?Wp2:Wc2;
  int maxr = (seg==0)?511:(seg==1)?99:0;
  int xoff4 = (seg==0)?256:(seg==1)?512:0;
  const float4* X4 = (const float4*)tcvp;
  float acc[4][4] = {};
  for (int kc=0; kc<2; kc++){
    for (int idx=tid; idx<2048; idx+=256){
      int cc = idx>>7, i = idx&127;
      xl[cc*129+i] = X4[(size_t)(blockIdx.y*16+cc)*768 + xoff4 + kc*128 + i];
    }
    __syncthreads();
    const float4* w0 = (const float4*)(WS + (size_t)min(rl0+0,maxr)*1024) + kc*128;
    const float4* w1 = (const float4*)(WS + (size_t)min(rl0+1,maxr)*1024) + kc*128;
    const float4* w2 = (const float4*)(WS + (size_t)min(rl0+2,maxr)*1024) + kc*128;
    const float4* w3 = (const float4*)(WS + (size_t)min(rl0+3,maxr)*1024) + kc*128;
    core_chunk(w0,w1,w2,w3, xl, l, g, acc);
    __syncthreads();
  }
  float v = reduce_pick(acc, l);
  int rl = rl0 + (l>>2);
  int n = blockIdx.y*16 + g*4 + (l&3);
  if (seg==0) kvh[(size_t)n*512 + rl] = f2bf(v + bv2[rl]);
  else if (seg==1){ if (rl < 100) kpall[n*128 + rl] = v + bp2[rl]; }
  else { if (rl == 0) zlall[n] = v + bc2[0]; }
}

// vocab GEMM (bf16 MFMA, 64x64 per wave) with fused per-64-row logsumexp partials
__global__ __launch_bounds__(256) void k2_vocab(
  const unsigned short* __restrict__ embh, const unsigned short* __restrict__ kvh,
  float2* __restrict__ part)
{
  int wid = blockIdx.x*4 + (threadIdx.x>>6);
  int lane = threadIdx.x & 63;
  int mtile = wid % 500, ntile = wid / 500;
  int mrow = mtile*64 + (lane&15);
  int ncol = ntile*64 + (lane&15);
  int ko = (lane>>4)*8;
  f4v acc[4][4];
  #pragma unroll
  for (int i=0;i<4;i++)
  #pragma unroll
  for (int j=0;j<4;j++)
  #pragma unroll
  for (int r=0;r<4;r++) acc[i][j][r] = 0.f;
  for (int kk=0; kk<512; kk+=32){
    short8 af[4], bfr[4];
    #pragma unroll
    for (int i=0;i<4;i++)
      af[i] = *(const short8*)(embh + (size_t)(mrow+16*i)*512 + kk + ko);
    #pragma unroll
    for (int i=0;i<4;i++)
      bfr[i] = *(const short8*)(kvh + (size_t)(ncol+16*i)*512 + kk + ko);
    #pragma unroll
    for (int i=0;i<4;i++)
      #pragma unroll
      for (int j=0;j<4;j++)
        acc[i][j] = __builtin_amdgcn_mfma_f32_16x16x32_bf16(af[i], bfr[j], acc[i][j], 0,0,0);
  }
  int q = lane>>4;
  #pragma unroll
  for (int j=0;j<4;j++){
    float mx = -3.4e38f;
    #pragma unroll
    for (int i=0;i<4;i++)
    #pragma unroll
    for (int r=0;r<4;r++) mx = fmaxf(mx, acc[i][j][r]);
    mx = fmaxf(mx, __shfl_xor(mx,16));
    mx = fmaxf(mx, __shfl_xor(mx,32));
    float s = 0.f;
    #pragma unroll
    for (int i=0;i<4;i++)
    #pragma unroll
    for (int r=0;r<4;r++) s += expf(acc[i][j][r] - mx);
    s += __shfl_xor(s,16);
    s += __shfl_xor(s,32);
    if (q==0){
      int col = ntile*64 + 16*j + (lane&15);
      part[(size_t)col*500 + mtile] = make_float2(mx, s);
    }
  }
}

// per-n: merge partials -> logZ; direct dot for logit[w]; vocab loss (z==0)
__global__ __launch_bounds__(256) void k2_vfin(
  const float2* __restrict__ part, const unsigned short* __restrict__ embh,
  const unsigned short* __restrict__ kvh, const int* __restrict__ tw,
  const int* __restrict__ tz, float* __restrict__ loss)
{
  __shared__ float red[4];
  int n = blockIdx.x, tid = threadIdx.x;
  int t = n>>4, b = n&15;
  float mx = -3.4e38f;
  for (int i=tid; i<500; i+=256) mx = fmaxf(mx, part[(size_t)n*500+i].x);
  #pragma unroll
  for (int m=32;m>0;m>>=1) mx = fmaxf(mx, __shfl_xor(mx,m));
  if ((tid&63)==0) red[tid>>6] = mx;
  __syncthreads();
  float M = fmaxf(fmaxf(red[0],red[1]), fmaxf(red[2],red[3]));
  __syncthreads();
  float s = 0.f;
  for (int i=tid; i<500; i+=256){
    float2 p = part[(size_t)n*500+i];
    s += p.y * expf(p.x - M);
  }
  s = wsum64(s);
  if ((tid&63)==0) red[tid>>6] = s;
  __syncthreads();
  float S = red[0]+red[1]+red[2]+red[3];
  __syncthreads();
  int w = tw[b*96+t];
  float d = 0.f;
  {
    const unsigned short* er = embh + (size_t)w*512;
    const unsigned short* kr = kvh + (size_t)n*512;
    for (int i=tid; i<512; i+=256) d += bf2f(er[i])*bf2f(kr[i]);
  }
  d = wsum64(d);
  if ((tid&63)==0) red[tid>>6] = d;
  __syncthreads();
  if (tid==0 && tz[b*96+t]==0){
    float D = red[0]+red[1]+red[2]+red[3];
    atomicAdd(loss, -(D - (M + logf(S))));
  }
}

// per-n: z loss + position loss
__global__ __launch_bounds__(128) void k2_posz(
  const float* __restrict__ kpall, const float* __restrict__ zlall,
  const float* __restrict__ WP, const float* __restrict__ bP,
  const float* __restrict__ pmask, const int* __restrict__ tw,
  const int* __restrict__ ta, const int* __restrict__ tz,
  float* __restrict__ loss)
{
  __shared__ float pp[100];
  int n = blockIdx.x, tid = threadIdx.x;
  int t = n>>4, b = n&15;
  if (tid < 100){
    float s = bP[tid];
    const float* wr = WP + tid*100;
    const float* kp = kpall + n*128;
    for (int j=0;j<100;j++) s += wr[j]*kp[j];
    pp[tid] = s;
  }
  __syncthreads();
  if (tid == 0){
    float u = zlall[n];
    int z = tz[b*96+t], w = tw[b*96+t], at = ta[b*96+t];
    float tot = z ? softplus(-u) : softplus(u);
    if (z){
      float mxv = -1e30f;
      for (int l2=0;l2<100;l2++) mxv = fmaxf(mxv, pp[l2]);
      float se = 0.f;
      for (int l2=0;l2<100;l2++) se += expf(pp[l2]-mxv);
      const float* pm = pmask + ((size_t)b*64 + at)*100;
      float msum = 0.f, mw = 0.f;
      for (int l2=0;l2<100;l2++){
        float m = pm[l2]*(expf(pp[l2]-mxv)/se) + EPSF;
        msum += m;
        if (l2==w) mw = m;
      }
      tot += -(logf(mw) - logf(msum));
    }
    atomicAdd(loss, tot);
  }
}

// ---------------- phase 0: once-per-launch precompute ----------------

__global__ void k_cvt_emb(const float* __restrict__ emb, unsigned* __restrict__ out){
  const int n = VV*512/2;
  for (int idx = blockIdx.x*256 + threadIdx.x; idx < n; idx += gridDim.x*256){
    float2 v = ((const float2*)emb)[idx];
    unsigned a = __float_as_uint(v.x), b = __float_as_uint(v.y);
    unsigned ra = (a + 0x7fffu + ((a>>16)&1u)) >> 16;
    unsigned rb = (b + 0x7fffu + ((b>>16)&1u)) >> 16;
    out[idx] = ra | (rb<<16);
  }
}

__global__ void k_setup(const float* __restrict__ fe, const int* __restrict__ nfp,
                        float* __restrict__ e_k){
  int b = blockIdx.x, tid = threadIdx.x;
  int nf = nfp[b];
  for (int d=tid; d<512; d+=256){
    float s = 0.f;
    for (int f=0; f<nf; f++) s += fe[((size_t)b*64+f)*512 + d];
    e_k[b*512+d] = s/(float)nf;
  }
}

__global__ __launch_bounds__(256) void k_pre_pa(
  const float* __restrict__ Wih, const float* __restrict__ fe, float* __restrict__ Pa)
{
  __shared__ float4 xl[16*129];
  int tid = threadIdx.x, lane = tid & 63, wave = tid >> 6;
  int l = lane & 15, g = lane >> 4;
  int row0 = blockIdx.x*16 + wave*4;
  int c0 = blockIdx.y*16;
  const float4* fe4 = (const float4*)fe;
  for (int idx=tid; idx<2048; idx+=256){
    int cc = idx>>7, i = idx&127;
    xl[cc*129+i] = fe4[(size_t)(c0+cc)*128 + i];
  }
  __syncthreads();
  const float4* w0 = (const float4*)(Wih + (size_t)(row0+0)*1124);
  const float4* w1 = (const float4*)(Wih + (size_t)(row0+1)*1124);
  const float4* w2 = (const float4*)(Wih + (size_t)(row0+2)*1124);
  const float4* w3 = (const float4*)(Wih + (size_t)(row0+3)*1124);
  float acc[4][4] = {};
  core_chunk(w0,w1,w2,w3, xl, l, g, acc);
  float v = reduce_pick(acc, l);
  int row = row0 + (l>>2), c = c0 + g*4 + (l&3);
  Pa[(size_t)c*4096 + row] = v;
}

__global__ __launch_bounds__(256) void k_pre_ph(
  const float* __restrict__ Wc1, const float* __restrict__ Wv1,
  const float* __restrict__ Wp1, const float* __restrict__ fe, float* __restrict__ Ph)
{
  __shared__ float4 xl[16*129];
  int tid = threadIdx.x, lane = tid & 63, wave = tid >> 6;
  int l = lane & 15, g = lane >> 4;
  int row0 = blockIdx.x*16 + wave*4;
  int head = row0 >> 10, rl0 = row0 & 1023;
  const float* W = (head==0)?Wc1:(head==1)?Wv1:Wp1;
  int c0 = blockIdx.y*16;
  const float4* fe4 = (const float4*)fe;
  for (int idx=tid; idx<2048; idx+=256){
    int cc = idx>>7, i = idx&127;
    xl[cc*129+i] = fe4[(size_t)(c0+cc)*128 + i];
  }
  __syncthreads();
  const float4* w0 = (const float4*)(W + (size_t)(rl0+0)*1536 + 1024);
  const float4* w1 = (const float4*)(W + (size_t)(rl0+1)*1536 + 1024);
  const float4* w2 = (const float4*)(W + (size_t)(rl0+2)*1536 + 1024);
  const float4* w3 = (const float4*)(W + (size_t)(rl0+3)*1536 + 1024);
  float acc[4][4] = {};
  core_chunk(w0,w1,w2,w3, xl, l, g, acc);
  float v = reduce_pick(acc, l);
  int row = row0 + (l>>2), c = c0 + g*4 + (l&3);
  Ph[(size_t)c*3072 + row] = v;
}

__global__ __launch_bounds__(256) void k_pre_pw(
  const float* __restrict__ Wih, const float* __restrict__ emb,
  const int* __restrict__ tw, const int* __restrict__ tz,
  const float* __restrict__ bih, const float* __restrict__ bhh,
  float* __restrict__ Pw)
{
  __shared__ float4 xl[16*129];
  int tid = threadIdx.x, lane = tid & 63, wave = tid >> 6;
  int l = lane & 15, g = lane >> 4;
  int row0 = blockIdx.x*16 + wave*4;
  int c0 = blockIdx.y*16;
  for (int idx=tid; idx<2048; idx+=256){
    int cc = idx>>7, i = idx&127;
    int c = c0+cc, b = c/96, t2 = c - b*96;
    int w=0, z=0;
    if (t2>0){ w = tw[b*96+t2-1]; z = tz[b*96+t2-1]; }
    float4 v = make_float4(0.f,0.f,0.f,0.f);
    if (z==0) v = ((const float4*)emb)[(size_t)w*128 + i];
    xl[cc*129+i] = v;
  }
  __syncthreads();
  const float4* w0 = (const float4*)(Wih + (size_t)(row0+0)*1124 + 512);
  const float4* w1 = (const float4*)(Wih + (size_t)(row0+1)*1124 + 512);
  const float4* w2 = (const float4*)(Wih + (size_t)(row0+2)*1124 + 512);
  const float4* w3 = (const float4*)(Wih + (size_t)(row0+3)*1124 + 512);
  float acc[4][4] = {};
  core_chunk(w0,w1,w2,w3, xl, l, g, acc);
  float v = reduce_pick(acc, l);
  int row = row0 + (l>>2), c = c0 + g*4 + (l&3);
  int b = c/96, t2 = c - b*96;
  int w=0, z=0;
  if (t2>0){ w = tw[b*96+t2-1]; z = tz[b*96+t2-1]; }
  v += bih[row] + bhh[row];
  if (z) v += Wih[(size_t)row*1124 + 1024 + w];
  Pw[(size_t)c*4096 + row] = v;
}

__global__ __launch_bounds__(256) void k_pre_cf(
  const float* __restrict__ Wf1, const float* __restrict__ bf1,
  const float* __restrict__ e_k, float* __restrict__ cf)
{
  __shared__ float4 xl[16*129];
  int tid = threadIdx.x, lane = tid & 63, wave = tid >> 6;
  int l = lane & 15, g = lane >> 4;
  int row0 = blockIdx.x*16 + wave*4;
  const float4* ek4 = (const float4*)e_k;
  for (int idx=tid; idx<2048; idx+=256){
    int cc = idx>>7, i = idx&127;
    xl[cc*129+i] = ek4[cc*128 + i];
  }
  __syncthreads();
  const float4* w0 = (const float4*)(Wf1 + (size_t)(row0+0)*1536 + 1024);
  const float4* w1 = (const float4*)(Wf1 + (size_t)(row0+1)*1536 + 1024);
  const float4* w2 = (const float4*)(Wf1 + (size_t)(row0+2)*1536 + 1024);
  const float4* w3 = (const float4*)(Wf1 + (size_t)(row0+3)*1536 + 1024);
  float acc[4][4] = {};
  core_chunk(w0,w1,w2,w3, xl, l, g, acc);
  float v = reduce_pick(acc, l);
  int row = row0 + (l>>2), b = g*4 + (l&3);
  cf[b*1024 + row] = v + bf1[row];
}

// Gb[(b*64+f)][k] = sum_d fe[b,f,d] * Wf2[d][k]   (1024 x 1024, K=512)
__global__ __launch_bounds__(256) void k_pre_g(
  const float* __restrict__ Wf2, const float* __restrict__ fe, float* __restrict__ Gb)
{
  __shared__ float fs[16][128];
  int tid = threadIdx.x;
  int r0 = blockIdx.x*16;
  int k0 = blockIdx.y*256;
  float acc[16] = {};
  for (int dc=0; dc<4; dc++){
    for (int idx=tid; idx<2048; idx+=256){
      int r = idx>>7, d = idx&127;
      fs[r][d] = fe[(size_t)(r0+r)*512 + dc*128 + d];
    }
    __syncthreads();
    for (int d=0; d<128; d++){
      float w = Wf2[(size_t)(dc*128+d)*1024 + k0 + tid];
      #pragma unroll
      for (int r=0;r<16;r++) acc[r] += fs[r][d]*w;
    }
    __syncthreads();
  }
  #pragma unroll
  for (int r=0;r<16;r++) Gb[(size_t)(r0+r)*1024 + k0 + tid] = acc[r];
}

// gb0[b,f] = fe[b,f,:] . bf2
__global__ __launch_bounds__(256) void k_gb0(
  const float* __restrict__ fe, const float* __restrict__ bf2, float* __restrict__ gb0)
{
  int b = blockIdx.x;
  int f = threadIdx.x>>2, q = threadIdx.x&3;
  const float4* fe4 = (const float4*)(fe + ((size_t)b*64+f)*512);
  const float4* b4 = (const float4*)bf2;
  float acc = 0.f;
  for (int j=0;j<32;j++){
    int i = q*32+j;
    float4 a = fe4[i], x = b4[i];
    acc += a.x*x.x + a.y*x.y + a.z*x.z + a.w*x.w;
  }
  acc += __shfl_xor(acc,1);
  acc += __shfl_xor(acc,2);
  if (q==0) gb0[b*64+f] = acc;
}

__global__ void k_out(const float* __restrict__ loss, float* __restrict__ out){
  out[0] = loss[0];
}

extern "C" void kernel_launch(void* const* d_in, const int* in_sizes, int n_in,
                              void* d_out, int out_size, void* d_ws, size_t ws_size,
                              hipStream_t stream)
{
  const float* fe   = (const float*)d_in[0];
  const float* pmask= (const float*)d_in[1];
  const float* emb  = (const float*)d_in[2];
  const float* Wih  = (const float*)d_in[3];
  const float* Whh  = (const float*)d_in[4];
  const float* bih  = (const float*)d_in[5];
  const float* bhh  = (const float*)d_in[6];
  const float* Wf1  = (const float*)d_in[7];
  const float* bf1  = (const float*)d_in[8];
  const float* Wf2  = (const float*)d_in[9];
  const float* bf2  = (const float*)d_in[10];
  const float* Wc1  = (const float*)d_in[11];
  const float* bc1  = (const float*)d_in[12];
  const float* Wc2  = (const float*)d_in[13];
  const float* bc2  = (const float*)d_in[14];
  const float* Wv1  = (const float*)d_in[15];
  const float* bv1  = (const float*)d_in[16];
  const float* Wv2  = (const float*)d_in[17];
  const float* bv2  = (const float*)d_in[18];
  const float* Wp1  = (const float*)d_in[19];
  const float* bp1  = (const float*)d_in[20];
  const float* Wp2  = (const float*)d_in[21];
  const float* bp2  = (const float*)d_in[22];
  const float* WP   = (const float*)d_in[23];
  const float* bP   = (const float*)d_in[24];
  const int* tw  = (const int*)d_in[25];
  const int* ta  = (const int*)d_in[26];
  const int* tz  = (const int*)d_in[27];
  const int* nfp = (const int*)d_in[28];

  float* w = (float*)d_ws;
  // layout (floats), all regions 256B-aligned; hall slots 64KB+256B-aligned so
  // no cache-fill granule spans a not-yet-written slot; aall padded 64 ints/t.
  float*    loss  = w + 0;                        // line 0: loss + bar only (LLC-side atomics)
  unsigned* bar   = (unsigned*)(w + 8);
  float*    c     = w + 64;                       // 16384 -> 16448
  float*    hall  = w + 16448;                    // 97*16384 = 1589248 -> 1605696
  int*      aall  = (int*)(w + 1605696);          // 96*64 ints -> 1611840
  float*    tf    = w + 1611840;                  // 16384 -> 1628224
  float*    gb0   = w + 1628224;                  // 1024 -> 1629248
  float*    e_k   = w + 1629248;                  // 8192 -> 1637440
  float*    cf    = w + 1637440;                  // 16384 -> 1653824
  float*    kpall = w + 1653824;                  // 196608 -> 1850432
  float*    zlall = w + 1850432;                  // 1536 -> 1851968
  float*    tcvp  = w + 1851968;                  // 4718592 -> 6570560 (phase 2 only)
  float*    Gb    = w + 1851968;                  // 1048576 — aliases tcvp; dead before k2_cvp
  float2*   part  = (float2*)(w + 6570560);       // 1536000 floats -> 8106560
  unsigned short* kvh = (unsigned short*)(w + 8106560); // 786432 ushorts -> 8499776
  float*    Pa    = w + 8499776;                  // 4194304 -> 12694080
  float*    Ph    = w + 12694080;                 // 3145728 -> 15839808
  float*    Pw    = w + 15839808;                 // 6291456 -> 22131264
  unsigned* embbf = (unsigned*)(w + 22131264);    // 8192000 uints
  const unsigned short* embh = (const unsigned short*)embbf;

  // zero loss, bar, c, hall slot 0   (floats 0 .. 32832)
  hipMemsetAsync(d_ws, 0, (size_t)32832*4, stream);
  k_cvt_emb<<<8192,256,0,stream>>>(emb, embbf);
  k_setup<<<16,256,0,stream>>>(fe, nfp, e_k);
  k_pre_pa<<<dim3(256,64),256,0,stream>>>(Wih, fe, Pa);
  k_pre_ph<<<dim3(192,64),256,0,stream>>>(Wc1, Wv1, Wp1, fe, Ph);
  k_pre_pw<<<dim3(256,96),256,0,stream>>>(Wih, emb, tw, tz, bih, bhh, Pw);
  k_pre_cf<<<64,256,0,stream>>>(Wf1, bf1, e_k, cf);
  k_pre_g<<<dim3(64,4),256,0,stream>>>(Wf2, fe, Gb);
  k_gb0<<<16,256,0,stream>>>(fe, bf2, gb0);

  // phase 1: one persistent kernel, fence-free grid barrier (graph-capture safe)
  k_phase1<<<256,256,0,stream>>>(Whh, hall, Pw, Pa, aall, c, Wf1, cf, tf,
                                 Gb, gb0, ta, nfp, loss, bar);

  k2_cvp<<<dim3(192,96),256,0,stream>>>(Wc1, Wv1, Wp1, hall, Ph, aall,
                                        bc1, bv1, bp1, tcvp);
  k2_heads2<<<dim3(40,96),256,0,stream>>>(Wv2, bv2, Wp2, bp2, Wc2, bc2,
                                          tcvp, kvh, kpall, zlall);
  k2_vocab<<<3000,256,0,stream>>>(embh, kvh, part);
  k2_vfin<<<1536,256,0,stream>>>(part, embh, kvh, tw, tz, loss);
  k2_posz<<<1536,128,0,stream>>>(kpall, zlall, WP, bP, pmask, tw, ta, tz, loss);
  k_out<<<1,1,0,stream>>>(loss, (float*)d_out);
}

// Round 4
// 4630.193 us; speedup vs baseline: 3.3126x; 1.1672x over previous
//
#include <hip/hip_runtime.h>
#include <math.h>

#define TT 96
#define VV 32000
#define EPSF 1e-8f

typedef __attribute__((ext_vector_type(8))) short short8;
typedef __attribute__((ext_vector_type(4))) float f4v;

__device__ __forceinline__ float wsum64(float v){
  #pragma unroll
  for (int m=32;m>0;m>>=1) v += __shfl_xor(v,m);
  return v;
}
__device__ __forceinline__ float sigm(float x){ return 1.0f/(1.0f+expf(-x)); }
__device__ __forceinline__ float softplus(float x){ return x>20.0f ? x : log1pf(expf(x)); }
__device__ __forceinline__ float bf2f(unsigned short u){ return __uint_as_float(((unsigned)u)<<16); }
__device__ __forceinline__ unsigned short f2bf(float f){
  unsigned u = __float_as_uint(f);
  return (unsigned short)((u + 0x7fffu + ((u>>16)&1u)) >> 16);
}

// Device-coherent (cache-bypassing) relaxed ops for cross-wg data.
__device__ __forceinline__ void st_dc(float* p, float v){
  __hip_atomic_store(p, v, __ATOMIC_RELAXED, __HIP_MEMORY_SCOPE_AGENT);
}
__device__ __forceinline__ void st_dc_i(int* p, int v){
  __hip_atomic_store(p, v, __ATOMIC_RELAXED, __HIP_MEMORY_SCOPE_AGENT);
}
__device__ __forceinline__ int ld_dc_i(const int* p){
  return __hip_atomic_load(p, __ATOMIC_RELAXED, __HIP_MEMORY_SCOPE_AGENT);
}
__device__ __forceinline__ unsigned ld_cnt(const unsigned* p){
  return __hip_atomic_load(p, __ATOMIC_RELAXED, __HIP_MEMORY_SCOPE_AGENT);
}
__device__ __forceinline__ float2 ld_dc_2(const float* p){
  union { unsigned long long u; float2 f; } cv;
  cv.u = __hip_atomic_load((const unsigned long long*)p, __ATOMIC_RELAXED, __HIP_MEMORY_SCOPE_AGENT);
  return cv.f;
}

// Hierarchical fence-free full barrier: 8 spread arrival counters (wg&7,
// 256B apart) + release epoch published by wg0. Monotone, no reset.
// Ordering: __syncthreads() drains each wave's vmcnt (sc-stores complete at
// the coherence point) before the arrival add — model validated in r3.
__device__ __forceinline__ void bar_full(unsigned* cntA, unsigned* rel, unsigned epoch){
  __syncthreads();
  if (threadIdx.x == 0)
    __hip_atomic_fetch_add(cntA + (blockIdx.x & 7)*64, 1u, __ATOMIC_RELAXED, __HIP_MEMORY_SCOPE_AGENT);
  if (blockIdx.x == 0){
    if (threadIdx.x < 64){
      unsigned tgt = epoch * 32u;
      while (true){
        unsigned v = (threadIdx.x < 8) ? ld_cnt(cntA + threadIdx.x*64) : tgt;
        if (__all(v >= tgt)) break;
        __builtin_amdgcn_s_sleep(1);
      }
      if (threadIdx.x == 0)
        __hip_atomic_store(rel, epoch, __ATOMIC_RELAXED, __HIP_MEMORY_SCOPE_AGENT);
    }
  } else {
    if (threadIdx.x == 0){
      while (ld_cnt(rel) < epoch) __builtin_amdgcn_s_sleep(1);
    }
  }
  __syncthreads();
}

// Core: 4 rows/wave, 16 cols (4 col-groups of 4), K-chunk of 512 split over 16 lanes.
__device__ __forceinline__ void core_chunk(
  const float4* __restrict__ w0, const float4* __restrict__ w1,
  const float4* __restrict__ w2, const float4* __restrict__ w3,
  const float4* __restrict__ xl, int l, int g, float (&acc)[4][4])
{
  #pragma unroll
  for (int kt=0; kt<8; kt++){
    int i = kt*16 + l;
    float4 a0=w0[i], a1=w1[i], a2=w2[i], a3=w3[i];
    #pragma unroll
    for (int j=0;j<4;j++){
      float4 x = xl[(4*g+j)*129 + i];
      acc[0][j] += a0.x*x.x + a0.y*x.y + a0.z*x.z + a0.w*x.w;
      acc[1][j] += a1.x*x.x + a1.y*x.y + a1.z*x.z + a1.w*x.w;
      acc[2][j] += a2.x*x.x + a2.y*x.y + a2.z*x.z + a2.w*x.w;
      acc[3][j] += a3.x*x.x + a3.y*x.y + a3.z*x.z + a3.w*x.w;
    }
  }
}

__device__ __forceinline__ float reduce_pick(float (&acc)[4][4], int l){
  float r = 0.f;
  #pragma unroll
  for (int ri=0;ri<4;ri++)
  #pragma unroll
  for (int j=0;j<4;j++){
    float v = acc[ri][j];
    v += __shfl_xor(v,1); v += __shfl_xor(v,2);
    v += __shfl_xor(v,4); v += __shfl_xor(v,8);
    if (l == ri*4+j) r = v;
  }
  return r;
}

// ---------------- phase 1: persistent recurrence ----------------
// 256 wgs x 256 thr. Per step ONE full barrier + two point-to-point waits:
//   A (all wgs):      poll aall[t-1] (uncached, write-once nonzero); gates; LSTM -> h(t+1)
//   [bar_full]
//   B (wgs 0..63):    tf[t&1] = relu(Wf1_h @ h(t+1) + cf); signal cntB (8 spread ctrs)
//   C (wgs 240..255): wait cntB; score = Gb·tf + gb0; softmax/argmax/loss; aall[t]=ai+1
__global__ __launch_bounds__(256) void k_phase1(
  const float* __restrict__ Whh, float* __restrict__ hall,
  const float* __restrict__ Pw, const float* __restrict__ Pa,
  int* __restrict__ aall, float* __restrict__ c,
  const float* __restrict__ Wf1, const float* __restrict__ cf,
  float* __restrict__ tf,
  const float* __restrict__ Gb, const float* __restrict__ gb0,
  const int* __restrict__ ta, const int* __restrict__ nfp,
  float* __restrict__ loss,
  unsigned* __restrict__ cntA, unsigned* __restrict__ cntB,
  unsigned* __restrict__ rel)
{
  __shared__ float4 xl[16*129];
  __shared__ float sg[256];
  __shared__ float sS[64];
  __shared__ int   sai[16];
  int tid = threadIdx.x, lane = tid & 63, wave = tid >> 6;
  int l = lane & 15, g = lane >> 4;
  int wg = blockIdx.x;

  for (int t=0; t<TT; t++){
    // ---- phase A: gates + LSTM pointwise (all wgs) ----
    {
      int j0 = wg*4;
      const float4* h4 = (const float4*)hall + (size_t)t*4096;
      float acc[4][4] = {};
      for (int kc=0; kc<2; kc++){
        for (int idx=tid; idx<2048; idx+=256){
          int b = idx>>7, i = idx&127;
          xl[b*129+i] = h4[b*256 + kc*128 + i];
        }
        __syncthreads();
        const float4* w0 = (const float4*)(Whh + (size_t)(wave*1024 + j0+0)*1024) + kc*128;
        const float4* w1 = (const float4*)(Whh + (size_t)(wave*1024 + j0+1)*1024) + kc*128;
        const float4* w2 = (const float4*)(Whh + (size_t)(wave*1024 + j0+2)*1024) + kc*128;
        const float4* w3 = (const float4*)(Whh + (size_t)(wave*1024 + j0+3)*1024) + kc*128;
        core_chunk(w0,w1,w2,w3, xl, l, g, acc);
        __syncthreads();
      }
      float v = reduce_pick(acc, l);
      // fetch ai(t-1): uncached poll of write-once slots (epoch-encoded ai+1)
      if (t > 0 && tid < 64){
        bool need = (tid < 16);
        while (true){
          int vv = need ? ld_dc_i(&aall[(t-1)*64 + tid]) : 1;
          if (__all(vv != 0)){ if (need) sai[tid] = vv - 1; break; }
          __builtin_amdgcn_s_sleep(1);
        }
      }
      __syncthreads();
      int r = l>>2;
      int b = g*4 + (l&3);
      int row = wave*1024 + j0 + r;
      float e = __builtin_nontemporal_load(Pw + ((size_t)(b*96+t))*4096 + row);
      if (t > 0){
        int ai = sai[b];
        e += __builtin_nontemporal_load(Pa + ((size_t)(b*64+ai))*4096 + row);
      }
      sg[wave*64 + r*16 + b] = v + e;
      __syncthreads();
      if (tid < 64){
        int jj = j0 + (tid>>4), bb = tid&15;
        float ig = sg[  0 + (tid>>4)*16 + bb];
        float fg = sg[ 64 + (tid>>4)*16 + bb];
        float gg = sg[128 + (tid>>4)*16 + bb];
        float og = sg[192 + (tid>>4)*16 + bb];
        int ci = bb*1024 + jj;
        float cn = sigm(fg)*c[ci] + sigm(ig)*tanhf(gg);
        c[ci] = cn;   // owner-exclusive (same wg/CU all steps): plain cached
        st_dc(&hall[((size_t)(t+1)*16 + bb)*1024 + jj], sigm(og)*tanhf(cn));
      }
    }
    bar_full(cntA, rel, (unsigned)(t+1));

    // ---- phase B: tf (wgs 0..63) ----
    if (wg < 64){
      int rl0 = wg*16 + wave*4;
      const float4* h4 = (const float4*)hall + (size_t)(t+1)*4096;
      float acc[4][4] = {};
      for (int kc=0; kc<2; kc++){
        for (int idx=tid; idx<2048; idx+=256){
          int b = idx>>7, i = idx&127;
          xl[b*129+i] = h4[b*256 + kc*128 + i];
        }
        __syncthreads();
        const float4* w0 = (const float4*)(Wf1 + (size_t)(rl0+0)*1536) + kc*128;
        const float4* w1 = (const float4*)(Wf1 + (size_t)(rl0+1)*1536) + kc*128;
        const float4* w2 = (const float4*)(Wf1 + (size_t)(rl0+2)*1536) + kc*128;
        const float4* w3 = (const float4*)(Wf1 + (size_t)(rl0+3)*1536) + kc*128;
        core_chunk(w0,w1,w2,w3, xl, l, g, acc);
        __syncthreads();
      }
      float v = reduce_pick(acc, l);
      int rl = rl0 + (l>>2);
      int b = g*4 + (l&3);
      float* tfb = tf + (t&1)*16384;
      st_dc(&tfb[b*1024 + rl], fmaxf(v + cf[b*1024 + rl], 0.f));
      __syncthreads();   // drain tf stores (vmcnt 0) before signaling
      if (tid == 0)
        __hip_atomic_fetch_add(cntB + (wg&7)*64, 1u, __ATOMIC_RELAXED, __HIP_MEMORY_SCOPE_AGENT);
    }

    // ---- phase C: scores + softmax + argmax + loss (wgs 240..255, b = wg-240) ----
    if (wg >= 240){
      int b = wg - 240;
      // wait for all 64 B-wgs (8 spread counters)
      if (tid < 64){
        unsigned tgt = (unsigned)(t+1) * 8u;
        while (true){
          unsigned vv = (tid < 8) ? ld_cnt(cntB + tid*64) : tgt;
          if (__all(vv >= tgt)) break;
          __builtin_amdgcn_s_sleep(1);
        }
      }
      __syncthreads();
      const float* tfb = tf + (t&1)*16384;
      float* stf = (float*)xl;
      {
        const float* src = tfb + b*1024;
        float2 c0 = ld_dc_2(src + 4*tid + 0);
        float2 c1 = ld_dc_2(src + 4*tid + 2);
        ((float2*)stf)[2*tid+0] = c0;
        ((float2*)stf)[2*tid+1] = c1;
      }
      __syncthreads();
      int f = tid>>2, q = tid&3;
      const float4* G4 = (const float4*)(Gb + (size_t)(b*64+f)*1024);
      const float4* st4 = (const float4*)stf;
      float acc = 0.f;
      for (int j=0;j<64;j++){
        int i = q*64 + j;
        float4 a = G4[i], x = st4[i];
        acc += a.x*x.x + a.y*x.y + a.z*x.z + a.w*x.w;
      }
      acc += __shfl_xor(acc,1);
      acc += __shfl_xor(acc,2);
      if (q==0) sS[f] = acc + gb0[b*64+f];
      __syncthreads();
      if (tid < 64){
        int nf = nfp[b];
        float s = sS[tid];
        float mx = s;
        #pragma unroll
        for (int m=32;m>0;m>>=1) mx = fmaxf(mx, __shfl_xor(mx,m));
        float p = expf(s - mx);
        float ps = wsum64(p);
        p /= ps;
        bool mask = (tid < nf) || (tid == 63);
        float mval = mask ? (p + EPSF) : EPSF;
        float msum = wsum64(mval);
        float bv = mval; int bi2 = tid;
        #pragma unroll
        for (int m=32;m>0;m>>=1){
          float ov = __shfl_xor(bv,m); int oi = __shfl_xor(bi2,m);
          if (ov > bv || (ov == bv && oi < bi2)){ bv = ov; bi2 = oi; }
        }
        int at = ta[b*TT + t];
        float mat = __shfl(mval, at);
        if (tid == 0){
          atomicAdd(loss, -(logf(mat) - logf(msum)));
          st_dc_i(&aall[t*64 + b], bi2 + 1);   // epoch-encoded: nonzero = ready
        }
      }
      __syncthreads();   // xl (stf) reuse protection before next step's staging
    }
  }
}

// ---------------- phase 2: batched over all (b,t) ----------------

// tcvp[n] = relu(W{c,v,p}1_h @ h_t + Ph[b,aidx] + bias), n = t*16+b
__global__ __launch_bounds__(256) void k2_cvp(
  const float* __restrict__ Wc1, const float* __restrict__ Wv1,
  const float* __restrict__ Wp1, const float* __restrict__ hall,
  const float* __restrict__ Ph, const int* __restrict__ aall,
  const float* __restrict__ bc1, const float* __restrict__ bv1,
  const float* __restrict__ bp1, float* __restrict__ tcvp)
{
  __shared__ float4 xl[16*129];
  int tid = threadIdx.x, lane = tid & 63, wave = tid >> 6;
  int l = lane & 15, g = lane >> 4;
  int seg = blockIdx.x >> 6;
  int rl0 = (blockIdx.x & 63)*16 + wave*4;
  const float* W = (seg==0)?Wc1:(seg==1)?Wv1:Wp1;
  const float4* h4 = (const float4*)hall + (size_t)(16 + blockIdx.y*16)*256;
  float acc[4][4] = {};
  for (int kc=0; kc<2; kc++){
    for (int idx=tid; idx<2048; idx+=256){
      int cc = idx>>7, i = idx&127;
      xl[cc*129+i] = h4[cc*256 + kc*128 + i];
    }
    __syncthreads();
    const float4* w0 = (const float4*)(W + (size_t)(rl0+0)*1536) + kc*128;
    const float4* w1 = (const float4*)(W + (size_t)(rl0+1)*1536) + kc*128;
    const float4* w2 = (const float4*)(W + (size_t)(rl0+2)*1536) + kc*128;
    const float4* w3 = (const float4*)(W + (size_t)(rl0+3)*1536) + kc*128;
    core_chunk(w0,w1,w2,w3, xl, l, g, acc);
    __syncthreads();
  }
  float v = reduce_pick(acc, l);
  int rl = rl0 + (l>>2);
  int n = blockIdx.y*16 + g*4 + (l&3);
  int b = n & 15;
  int ai = aall[(n>>4)*64 + (n&15)] - 1;
  const float* bias = (seg==0)?bc1:(seg==1)?bv1:bp1;
  float vv = v + Ph[((size_t)(b*64+ai))*3072 + seg*1024 + rl] + bias[rl];
  tcvp[(size_t)n*3072 + seg*1024 + rl] = fmaxf(vv, 0.f);
}

// kvoca(bf16) / kpos / zlog for all n
__global__ __launch_bounds__(256) void k2_heads2(
  const float* __restrict__ Wv2, const float* __restrict__ bv2,
  const float* __restrict__ Wp2, const float* __restrict__ bp2,
  const float* __restrict__ Wc2, const float* __restrict__ bc2,
  const float* __restrict__ tcvp, unsigned short* __restrict__ kvh,
  float* __restrict__ kpall, float* __restrict__ zlall)
{
  __shared__ float4 xl[16*129];
  int tid = threadIdx.x, lane = tid & 63, wave = tid >> 6;
  int l = lane & 15, g = lane >> 4;
  int bx = blockIdx.x;
  int seg = (bx < 32) ? 0 : (bx < 39) ? 1 : 2;
  int rb  = (seg==0) ? bx*16 : (seg==1) ? (bx-32)*16 : 0;
  int rl0 = rb + wave*4;
  const float* WS = (seg==0)?Wv2:(seg==1)?Wp2:Wc2;
  int maxr = (seg==0)?511:(seg==1)?99:0;
  int xoff4 = (seg==0)?256:(seg==1)?512:0;
  const float4* X4 = (const float4*)tcvp;
  float acc[4][4] = {};
  for (int kc=0; kc<2; kc++){
    for (int idx=tid; idx<2048; idx+=256){
      int cc = idx>>7, i = idx&127;
      xl[cc*129+i] = X4[(size_t)(blockIdx.y*16+cc)*768 + xoff4 + kc*128 + i];
    }
    __syncthreads();
    const float4* w0 = (const float4*)(WS + (size_t)min(rl0+0,maxr)*1024) + kc*128;
    const float4* w1 = (const float4*)(WS + (size_t)min(rl0+1,maxr)*1024) + kc*128;
    const float4* w2 = (const float4*)(WS + (size_t)min(rl0+2,maxr)*1024) + kc*128;
    const float4* w3 = (const float4*)(WS + (size_t)min(rl0+3,maxr)*1024) + kc*128;
    core_chunk(w0,w1,w2,w3, xl, l, g, acc);
    __syncthreads();
  }
  float v = reduce_pick(acc, l);
  int rl = rl0 + (l>>2);
  int n = blockIdx.y*16 + g*4 + (l&3);
  if (seg==0) kvh[(size_t)n*512 + rl] = f2bf(v + bv2[rl]);
  else if (seg==1){ if (rl < 100) kpall[n*128 + rl] = v + bp2[rl]; }
  else { if (rl == 0) zlall[n] = v + bc2[0]; }
}

// vocab GEMM (bf16 MFMA, 64x64 per wave) with fused per-64-row logsumexp partials
__global__ __launch_bounds__(256) void k2_vocab(
  const unsigned short* __restrict__ embh, const unsigned short* __restrict__ kvh,
  float2* __restrict__ part)
{
  int wid = blockIdx.x*4 + (threadIdx.x>>6);
  int lane = threadIdx.x & 63;
  int mtile = wid % 500, ntile = wid / 500;
  int mrow = mtile*64 + (lane&15);
  int ncol = ntile*64 + (lane&15);
  int ko = (lane>>4)*8;
  f4v acc[4][4];
  #pragma unroll
  for (int i=0;i<4;i++)
  #pragma unroll
  for (int j=0;j<4;j++)
  #pragma unroll
  for (int r=0;r<4;r++) acc[i][j][r] = 0.f;
  for (int kk=0; kk<512; kk+=32){
    short8 af[4], bfr[4];
    #pragma unroll
    for (int i=0;i<4;i++)
      af[i] = *(const short8*)(embh + (size_t)(mrow+16*i)*512 + kk + ko);
    #pragma unroll
    for (int i=0;i<4;i++)
      bfr[i] = *(const short8*)(kvh + (size_t)(ncol+16*i)*512 + kk + ko);
    #pragma unroll
    for (int i=0;i<4;i++)
      #pragma unroll
      for (int j=0;j<4;j++)
        acc[i][j] = __builtin_amdgcn_mfma_f32_16x16x32_bf16(af[i], bfr[j], acc[i][j], 0,0,0);
  }
  int q = lane>>4;
  #pragma unroll
  for (int j=0;j<4;j++){
    float mx = -3.4e38f;
    #pragma unroll
    for (int i=0;i<4;i++)
    #pragma unroll
    for (int r=0;r<4;r++) mx = fmaxf(mx, acc[i][j][r]);
    mx = fmaxf(mx, __shfl_xor(mx,16));
    mx = fmaxf(mx, __shfl_xor(mx,32));
    float s = 0.f;
    #pragma unroll
    for (int i=0;i<4;i++)
    #pragma unroll
    for (int r=0;r<4;r++) s += expf(acc[i][j][r] - mx);
    s += __shfl_xor(s,16);
    s += __shfl_xor(s,32);
    if (q==0){
      int col = ntile*64 + 16*j + (lane&15);
      part[(size_t)col*500 + mtile] = make_float2(mx, s);
    }
  }
}

// per-n: merge partials -> logZ; direct dot for logit[w]; vocab loss (z==0)
__global__ __launch_bounds__(256) void k2_vfin(
  const float2* __restrict__ part, const unsigned short* __restrict__ embh,
  const unsigned short* __restrict__ kvh, const int* __restrict__ tw,
  const int* __restrict__ tz, float* __restrict__ loss)
{
  __shared__ float red[4];
  int n = blockIdx.x, tid = threadIdx.x;
  int t = n>>4, b = n&15;
  float mx = -3.4e38f;
  for (int i=tid; i<500; i+=256) mx = fmaxf(mx, part[(size_t)n*500+i].x);
  #pragma unroll
  for (int m=32;m>0;m>>=1) mx = fmaxf(mx, __shfl_xor(mx,m));
  if ((tid&63)==0) red[tid>>6] = mx;
  __syncthreads();
  float M = fmaxf(fmaxf(red[0],red[1]), fmaxf(red[2],red[3]));
  __syncthreads();
  float s = 0.f;
  for (int i=tid; i<500; i+=256){
    float2 p = part[(size_t)n*500+i];
    s += p.y * expf(p.x - M);
  }
  s = wsum64(s);
  if ((tid&63)==0) red[tid>>6] = s;
  __syncthreads();
  float S = red[0]+red[1]+red[2]+red[3];
  __syncthreads();
  int w = tw[b*96+t];
  float d = 0.f;
  {
    const unsigned short* er = embh + (size_t)w*512;
    const unsigned short* kr = kvh + (size_t)n*512;
    for (int i=tid; i<512; i+=256) d += bf2f(er[i])*bf2f(kr[i]);
  }
  d = wsum64(d);
  if ((tid&63)==0) red[tid>>6] = d;
  __syncthreads();
  if (tid==0 && tz[b*96+t]==0){
    float D = red[0]+red[1]+red[2]+red[3];
    atomicAdd(loss, -(D - (M + logf(S))));
  }
}

// per-n: z loss + position loss
__global__ __launch_bounds__(128) void k2_posz(
  const float* __restrict__ kpall, const float* __restrict__ zlall,
  const float* __restrict__ WP, const float* __restrict__ bP,
  const float* __restrict__ pmask, const int* __restrict__ tw,
  const int* __restrict__ ta, const int* __restrict__ tz,
  float* __restrict__ loss)
{
  __shared__ float pp[100];
  int n = blockIdx.x, tid = threadIdx.x;
  int t = n>>4, b = n&15;
  if (tid < 100){
    float s = bP[tid];
    const float* wr = WP + tid*100;
    const float* kp = kpall + n*128;
    for (int j=0;j<100;j++) s += wr[j]*kp[j];
    pp[tid] = s;
  }
  __syncthreads();
  if (tid == 0){
    float u = zlall[n];
    int z = tz[b*96+t], w = tw[b*96+t], at = ta[b*96+t];
    float tot = z ? softplus(-u) : softplus(u);
    if (z){
      float mxv = -1e30f;
      for (int l2=0;l2<100;l2++) mxv = fmaxf(mxv, pp[l2]);
      float se = 0.f;
      for (int l2=0;l2<100;l2++) se += expf(pp[l2]-mxv);
      const float* pm = pmask + ((size_t)b*64 + at)*100;
      float msum = 0.f, mw = 0.f;
      for (int l2=0;l2<100;l2++){
        float m = pm[l2]*(expf(pp[l2]-mxv)/se) + EPSF;
        msum += m;
        if (l2==w) mw = m;
      }
      tot += -(logf(mw) - logf(msum));
    }
    atomicAdd(loss, tot);
  }
}

// ---------------- phase 0: once-per-launch precompute ----------------

__global__ void k_cvt_emb(const float* __restrict__ emb, unsigned* __restrict__ out){
  const int n = VV*512/2;
  for (int idx = blockIdx.x*256 + threadIdx.x; idx < n; idx += gridDim.x*256){
    float2 v = ((const float2*)emb)[idx];
    unsigned a = __float_as_uint(v.x), b = __float_as_uint(v.y);
    unsigned ra = (a + 0x7fffu + ((a>>16)&1u)) >> 16;
    unsigned rb = (b + 0x7fffu + ((b>>16)&1u)) >> 16;
    out[idx] = ra | (rb<<16);
  }
}

__global__ void k_setup(const float* __restrict__ fe, const int* __restrict__ nfp,
                        float* __restrict__ e_k){
  int b = blockIdx.x, tid = threadIdx.x;
  int nf = nfp[b];
  for (int d=tid; d<512; d+=256){
    float s = 0.f;
    for (int f=0; f<nf; f++) s += fe[((size_t)b*64+f)*512 + d];
    e_k[b*512+d] = s/(float)nf;
  }
}

__global__ __launch_bounds__(256) void k_pre_pa(
  const float* __restrict__ Wih, const float* __restrict__ fe, float* __restrict__ Pa)
{
  __shared__ float4 xl[16*129];
  int tid = threadIdx.x, lane = tid & 63, wave = tid >> 6;
  int l = lane & 15, g = lane >> 4;
  int row0 = blockIdx.x*16 + wave*4;
  int c0 = blockIdx.y*16;
  const float4* fe4 = (const float4*)fe;
  for (int idx=tid; idx<2048; idx+=256){
    int cc = idx>>7, i = idx&127;
    xl[cc*129+i] = fe4[(size_t)(c0+cc)*128 + i];
  }
  __syncthreads();
  const float4* w0 = (const float4*)(Wih + (size_t)(row0+0)*1124);
  const float4* w1 = (const float4*)(Wih + (size_t)(row0+1)*1124);
  const float4* w2 = (const float4*)(Wih + (size_t)(row0+2)*1124);
  const float4* w3 = (const float4*)(Wih + (size_t)(row0+3)*1124);
  float acc[4][4] = {};
  core_chunk(w0,w1,w2,w3, xl, l, g, acc);
  float v = reduce_pick(acc, l);
  int row = row0 + (l>>2), c = c0 + g*4 + (l&3);
  Pa[(size_t)c*4096 + row] = v;
}

__global__ __launch_bounds__(256) void k_pre_ph(
  const float* __restrict__ Wc1, const float* __restrict__ Wv1,
  const float* __restrict__ Wp1, const float* __restrict__ fe, float* __restrict__ Ph)
{
  __shared__ float4 xl[16*129];
  int tid = threadIdx.x, lane = tid & 63, wave = tid >> 6;
  int l = lane & 15, g = lane >> 4;
  int row0 = blockIdx.x*16 + wave*4;
  int head = row0 >> 10, rl0 = row0 & 1023;
  const float* W = (head==0)?Wc1:(head==1)?Wv1:Wp1;
  int c0 = blockIdx.y*16;
  const float4* fe4 = (const float4*)fe;
  for (int idx=tid; idx<2048; idx+=256){
    int cc = idx>>7, i = idx&127;
    xl[cc*129+i] = fe4[(size_t)(c0+cc)*128 + i];
  }
  __syncthreads();
  const float4* w0 = (const float4*)(W + (size_t)(rl0+0)*1536 + 1024);
  const float4* w1 = (const float4*)(W + (size_t)(rl0+1)*1536 + 1024);
  const float4* w2 = (const float4*)(W + (size_t)(rl0+2)*1536 + 1024);
  const float4* w3 = (const float4*)(W + (size_t)(rl0+3)*1536 + 1024);
  float acc[4][4] = {};
  core_chunk(w0,w1,w2,w3, xl, l, g, acc);
  float v = reduce_pick(acc, l);
  int row = row0 + (l>>2), c = c0 + g*4 + (l&3);
  Ph[(size_t)c*3072 + row] = v;
}

__global__ __launch_bounds__(256) void k_pre_pw(
  const float* __restrict__ Wih, const float* __restrict__ emb,
  const int* __restrict__ tw, const int* __restrict__ tz,
  const float* __restrict__ bih, const float* __restrict__ bhh,
  float* __restrict__ Pw)
{
  __shared__ float4 xl[16*129];
  int tid = threadIdx.x, lane = tid & 63, wave = tid >> 6;
  int l = lane & 15, g = lane >> 4;
  int row0 = blockIdx.x*16 + wave*4;
  int c0 = blockIdx.y*16;
  for (int idx=tid; idx<2048; idx+=256){
    int cc = idx>>7, i = idx&127;
    int c = c0+cc, b = c/96, t2 = c - b*96;
    int w=0, z=0;
    if (t2>0){ w = tw[b*96+t2-1]; z = tz[b*96+t2-1]; }
    float4 v = make_float4(0.f,0.f,0.f,0.f);
    if (z==0) v = ((const float4*)emb)[(size_t)w*128 + i];
    xl[cc*129+i] = v;
  }
  __syncthreads();
  const float4* w0 = (const float4*)(Wih + (size_t)(row0+0)*1124 + 512);
  const float4* w1 = (const float4*)(Wih + (size_t)(row0+1)*1124 + 512);
  const float4* w2 = (const float4*)(Wih + (size_t)(row0+2)*1124 + 512);
  const float4* w3 = (const float4*)(Wih + (size_t)(row0+3)*1124 + 512);
  float acc[4][4] = {};
  core_chunk(w0,w1,w2,w3, xl, l, g, acc);
  float v = reduce_pick(acc, l);
  int row = row0 + (l>>2), c = c0 + g*4 + (l&3);
  int b = c/96, t2 = c - b*96;
  int w=0, z=0;
  if (t2>0){ w = tw[b*96+t2-1]; z = tz[b*96+t2-1]; }
  v += bih[row] + bhh[row];
  if (z) v += Wih[(size_t)row*1124 + 1024 + w];
  Pw[(size_t)c*4096 + row] = v;
}

__global__ __launch_bounds__(256) void k_pre_cf(
  const float* __restrict__ Wf1, const float* __restrict__ bf1,
  const float* __restrict__ e_k, float* __restrict__ cf)
{
  __shared__ float4 xl[16*129];
  int tid = threadIdx.x, lane = tid & 63, wave = tid >> 6;
  int l = lane & 15, g = lane >> 4;
  int row0 = blockIdx.x*16 + wave*4;
  const float4* ek4 = (const float4*)e_k;
  for (int idx=tid; idx<2048; idx+=256){
    int cc = idx>>7, i = idx&127;
    xl[cc*129+i] = ek4[cc*128 + i];
  }
  __syncthreads();
  const float4* w0 = (const float4*)(Wf1 + (size_t)(row0+0)*1536 + 1024);
  const float4* w1 = (const float4*)(Wf1 + (size_t)(row0+1)*1536 + 1024);
  const float4* w2 = (const float4*)(Wf1 + (size_t)(row0+2)*1536 + 1024);
  const float4* w3 = (const float4*)(Wf1 + (size_t)(row0+3)*1536 + 1024);
  float acc[4][4] = {};
  core_chunk(w0,w1,w2,w3, xl, l, g, acc);
  float v = reduce_pick(acc, l);
  int row = row0 + (l>>2), b = g*4 + (l&3);
  cf[b*1024 + row] = v + bf1[row];
}

// Gb[(b*64+f)][k] = sum_d fe[b,f,d] * Wf2[d][k]   (1024 x 1024, K=512)
__global__ __launch_bounds__(256) void k_pre_g(
  const float* __restrict__ Wf2, const float* __restrict__ fe, float* __restrict__ Gb)
{
  __shared__ float fs[16][128];
  int tid = threadIdx.x;
  int r0 = blockIdx.x*16;
  int k0 = blockIdx.y*256;
  float acc[16] = {};
  for (int dc=0; dc<4; dc++){
    for (int idx=tid; idx<2048; idx+=256){
      int r = idx>>7, d = idx&127;
      fs[r][d] = fe[(size_t)(r0+r)*512 + dc*128 + d];
    }
    __syncthreads();
    for (int d=0; d<128; d++){
      float w = Wf2[(size_t)(dc*128+d)*1024 + k0 + tid];
      #pragma unroll
      for (int r=0;r<16;r++) acc[r] += fs[r][d]*w;
    }
    __syncthreads();
  }
  #pragma unroll
  for (int r=0;r<16;r++) Gb[(size_t)(r0+r)*1024 + k0 + tid] = acc[r];
}

// gb0[b,f] = fe[b,f,:] . bf2
__global__ __launch_bounds__(256) void k_gb0(
  const float* __restrict__ fe, const float* __restrict__ bf2, float* __restrict__ gb0)
{
  int b = blockIdx.x;
  int f = threadIdx.x>>2, q = threadIdx.x&3;
  const float4* fe4 = (const float4*)(fe + ((size_t)b*64+f)*512);
  const float4* b4 = (const float4*)bf2;
  float acc = 0.f;
  for (int j=0;j<32;j++){
    int i = q*32+j;
    float4 a = fe4[i], x = b4[i];
    acc += a.x*x.x + a.y*x.y + a.z*x.z + a.w*x.w;
  }
  acc += __shfl_xor(acc,1);
  acc += __shfl_xor(acc,2);
  if (q==0) gb0[b*64+f] = acc;
}

__global__ void k_out(const float* __restrict__ loss, float* __restrict__ out){
  out[0] = loss[0];
}

extern "C" void kernel_launch(void* const* d_in, const int* in_sizes, int n_in,
                              void* d_out, int out_size, void* d_ws, size_t ws_size,
                              hipStream_t stream)
{
  const float* fe   = (const float*)d_in[0];
  const float* pmask= (const float*)d_in[1];
  const float* emb  = (const float*)d_in[2];
  const float* Wih  = (const float*)d_in[3];
  const float* Whh  = (const float*)d_in[4];
  const float* bih  = (const float*)d_in[5];
  const float* bhh  = (const float*)d_in[6];
  const float* Wf1  = (const float*)d_in[7];
  const float* bf1  = (const float*)d_in[8];
  const float* Wf2  = (const float*)d_in[9];
  const float* bf2  = (const float*)d_in[10];
  const float* Wc1  = (const float*)d_in[11];
  const float* bc1  = (const float*)d_in[12];
  const float* Wc2  = (const float*)d_in[13];
  const float* bc2  = (const float*)d_in[14];
  const float* Wv1  = (const float*)d_in[15];
  const float* bv1  = (const float*)d_in[16];
  const float* Wv2  = (const float*)d_in[17];
  const float* bv2  = (const float*)d_in[18];
  const float* Wp1  = (const float*)d_in[19];
  const float* bp1  = (const float*)d_in[20];
  const float* Wp2  = (const float*)d_in[21];
  const float* bp2  = (const float*)d_in[22];
  const float* WP   = (const float*)d_in[23];
  const float* bP   = (const float*)d_in[24];
  const int* tw  = (const int*)d_in[25];
  const int* ta  = (const int*)d_in[26];
  const int* tz  = (const int*)d_in[27];
  const int* nfp = (const int*)d_in[28];

  float* w = (float*)d_ws;
  // layout (float offsets). Barrier state + c + hall slot0 zeroed by memset1;
  // aall zeroed by memset2 (polled-for-nonzero, must reset every launch).
  float*    loss  = w + 0;
  unsigned* cntA  = (unsigned*)(w + 64);          // 8 ctrs, stride 64 (256B)
  unsigned* cntB  = (unsigned*)(w + 576);         // 8 ctrs, stride 64
  unsigned* rel   = (unsigned*)(w + 1088);
  float*    c     = w + 2048;                     // 16384 -> 18432
  float*    hall  = w + 18432;                    // 97*16384 -> 1607680
  int*      aall  = (int*)(w + 1607680);          // 96*64 ints -> 1613824
  float*    tf    = w + 1613824;                  // 2 x 16384 -> 1646592
  float*    gb0   = w + 1646592;                  // 1024 -> 1647616
  float*    e_k   = w + 1647616;                  // 8192 -> 1655808
  float*    cf    = w + 1655808;                  // 16384 -> 1672192
  float*    kpall = w + 1672192;                  // 196608 -> 1868800
  float*    zlall = w + 1868800;                  // 1536 -> 1870336
  float*    tcvp  = w + 1870336;                  // 4718592 -> 6588928 (phase 2 only)
  float*    Gb    = w + 1870336;                  // 1048576 — aliases tcvp; dead before k2_cvp
  float2*   part  = (float2*)(w + 6588928);       // 1536000 floats -> 8124928
  unsigned short* kvh = (unsigned short*)(w + 8124928); // 786432 ushorts -> 8518144
  float*    Pa    = w + 8518144;                  // 4194304 -> 12712448
  float*    Ph    = w + 12712448;                 // 3145728 -> 15858176
  float*    Pw    = w + 15858176;                 // 6291456 -> 22149632
  unsigned* embbf = (unsigned*)(w + 22149632);    // 8192000 uints
  const unsigned short* embh = (const unsigned short*)embbf;

  // zero: loss/cntA/cntB/rel/c/hall-slot0 ; aall
  hipMemsetAsync(d_ws, 0, (size_t)34816*4, stream);
  hipMemsetAsync((void*)aall, 0, (size_t)96*64*4, stream);
  k_cvt_emb<<<8192,256,0,stream>>>(emb, embbf);
  k_setup<<<16,256,0,stream>>>(fe, nfp, e_k);
  k_pre_pa<<<dim3(256,64),256,0,stream>>>(Wih, fe, Pa);
  k_pre_ph<<<dim3(192,64),256,0,stream>>>(Wc1, Wv1, Wp1, fe, Ph);
  k_pre_pw<<<dim3(256,96),256,0,stream>>>(Wih, emb, tw, tz, bih, bhh, Pw);
  k_pre_cf<<<64,256,0,stream>>>(Wf1, bf1, e_k, cf);
  k_pre_g<<<dim3(64,4),256,0,stream>>>(Wf2, fe, Gb);
  k_gb0<<<16,256,0,stream>>>(fe, bf2, gb0);

  // phase 1: persistent kernel, 1 hierarchical barrier + p2p waits per step
  k_phase1<<<256,256,0,stream>>>(Whh, hall, Pw, Pa, aall, c, Wf1, cf, tf,
                                 Gb, gb0, ta, nfp, loss, cntA, cntB, rel);

  k2_cvp<<<dim3(192,96),256,0,stream>>>(Wc1, Wv1, Wp1, hall, Ph, aall,
                                        bc1, bv1, bp1, tcvp);
  k2_heads2<<<dim3(40,96),256,0,stream>>>(Wv2, bv2, Wp2, bp2, Wc2, bc2,
                                          tcvp, kvh, kpall, zlall);
  k2_vocab<<<3000,256,0,stream>>>(embh, kvh, part);
  k2_vfin<<<1536,256,0,stream>>>(part, embh, kvh, tw, tz, loss);
  k2_posz<<<1536,128,0,stream>>>(kpall, zlall, WP, bP, pmask, tw, ta, tz, loss);
  k_out<<<1,1,0,stream>>>(loss, (float*)d_out);
}